// Round 8
// baseline (1155.135 us; speedup 1.0000x reference)
//
#include <hip/hip_runtime.h>
#include <cfloat>
#include <cstddef>
#include <cstdint>

// ---------------------------------------------------------------------------
// SemanticRQVAE forward, round 7: fused residual VQ (all 4 stages, one kernel,
// residual resident in LDS). GEMM pipeline unchanged from round 6 (proven).
// Activation format, per row, per k-tile of 16 (64 B):
//   [u=0] h(k0..7) [u=1] h(k8..15) [u=2] l(k0..7) [u=3] l(k8..15)
// d_out layout (floats): recon (25165824) | indices as float (262144)
//                        | recon_loss | commit_loss
// ---------------------------------------------------------------------------

#define BATCH   65536
#define EDIM    384
#define HDIM    512
#define NCODE   256
#define NQ      4

#define OUT_IDX_OFF 25165824
#define OUT_RL_OFF  25427968
#define WS_P0       0
#define WS_P1       33554432
#define WS_CBSPL    67108864
#define WS_CNORM    67633152
#define WS_COMMITP  67634176
#define WS_RECONP   67636224
#define WS_W1S      67637760
#define WS_W2S      67834368
#define WS_W3S      68096512
#define WS_W4S      68358656

typedef _Float16 half8 __attribute__((ext_vector_type(8)));
typedef float    f32x16 __attribute__((ext_vector_type(16)));

__device__ __forceinline__ void cvt_hl8(const float* vs, half8& h, half8& l)
{
#pragma unroll
    for (int j = 0; j < 8; ++j) {
        _Float16 hv = (_Float16)vs[j];
        h[j] = hv;
        l[j] = (_Float16)(vs[j] - (float)hv);
    }
}

__device__ __forceinline__ void gll16(const unsigned short* g, unsigned short* l)
{
    __builtin_amdgcn_global_load_lds(
        (const __attribute__((address_space(1))) unsigned int*)g,
        (__attribute__((address_space(3))) unsigned int*)l, 16, 0, 0);
}

template <int N> __device__ __forceinline__ void waitvm()
{
    __builtin_amdgcn_sched_barrier(0);
    if constexpr (N == 0)      asm volatile("s_waitcnt vmcnt(0)" ::: "memory");
    else if constexpr (N == 4) asm volatile("s_waitcnt vmcnt(4)" ::: "memory");
    else if constexpr (N == 6) asm volatile("s_waitcnt vmcnt(6)" ::: "memory");
    __builtin_amdgcn_sched_barrier(0);
}
__device__ __forceinline__ void barrier_raw()
{
    __builtin_amdgcn_s_barrier();
    __builtin_amdgcn_sched_barrier(0);
}

// ---------------------------------------------------------------------------
// One-shot splits
// ---------------------------------------------------------------------------
__global__ __launch_bounds__(256)
void split_x(const float* __restrict__ x, unsigned short* __restrict__ xs)
{
    int u = blockIdx.x * 256 + threadIdx.x;       // BATCH * 48 units
    int row = u / 48;
    int rem = u % 48;
    int kt = rem >> 1, khalf = rem & 1;
    const float* p = x + (size_t)row * EDIM + kt * 16 + khalf * 8;
    float vs[8];
#pragma unroll
    for (int j = 0; j < 8; ++j) vs[j] = p[j];
    half8 h, l;
    cvt_hl8(vs, h, l);
    unsigned short* o = xs + (size_t)row * 768 + kt * 32 + khalf * 8;
    *reinterpret_cast<half8*>(o)      = h;
    *reinterpret_cast<half8*>(o + 16) = l;
}

__global__ __launch_bounds__(256)
void split_w(const float* __restrict__ W, unsigned short* __restrict__ out,
             int N, int K)
{
    int u = blockIdx.x * 256 + threadIdx.x;
    int col  = u % N;
    int rem  = u / N;
    int khalf = rem & 1;
    int kt    = rem >> 1;
    int kbase = kt * 16 + khalf * 8;
    float vs[8];
#pragma unroll
    for (int j = 0; j < 8; ++j) vs[j] = W[(size_t)(kbase + j) * N + col];
    half8 h, l;
    cvt_hl8(vs, h, l);
    *reinterpret_cast<half8*>(out + ((size_t)(kt * 4 + khalf) * N + col) * 8)     = h;
    *reinterpret_cast<half8*>(out + ((size_t)(kt * 4 + 2 + khalf) * N + col) * 8) = l;
}

__global__ __launch_bounds__(256)
void split_cb(const float* __restrict__ cb, unsigned short* __restrict__ out)
{
    int u = blockIdx.x * 256 + threadIdx.x;
    int q    = u >> 14;
    int rem  = u & 16383;
    int code = rem >> 6;
    int kt   = (rem >> 1) & 31;
    int khalf = rem & 1;
    int k = kt * 16 + khalf * 8;
    const float* p = cb + ((size_t)(q * NCODE + code)) * HDIM + k;
    float vs[8];
#pragma unroll
    for (int j = 0; j < 8; ++j) vs[j] = p[j];
    half8 h, l;
    cvt_hl8(vs, h, l);
    size_t o = (size_t)(q * 32 + kt) * 8192 + (size_t)khalf * 2048 + (size_t)code * 8;
    *reinterpret_cast<half8*>(out + o)        = h;
    *reinterpret_cast<half8*>(out + o + 4096) = l;
}

__global__ __launch_bounds__(64)
void cnorm_kernel(const float* __restrict__ cb, float* __restrict__ cnorm)
{
    const int code = blockIdx.x;
    const int lane = threadIdx.x;
    const float* r = cb + (size_t)code * HDIM;
    float s = 0.f;
    for (int k = lane; k < HDIM; k += 64) s = fmaf(r[k], r[k], s);
#pragma unroll
    for (int off = 32; off > 0; off >>= 1) s += __shfl_down(s, off);
    if (lane == 0) cnorm[code] = s;
}

// ---------------------------------------------------------------------------
// Pipelined MFMA GEMM (unchanged from round 6, correctness-proven).
// ---------------------------------------------------------------------------
template <int BN, int NKT, int OMODE, bool RELU>
__global__ __launch_bounds__(256, 2)
void gemm_pl(const unsigned short* __restrict__ Ain,
             const unsigned short* __restrict__ Wsp,
             const float* __restrict__ bias, void* __restrict__ Cout,
             const float* __restrict__ X, float* __restrict__ lossP, int N)
{
    constexpr int WN  = BN / 128;
    constexpr int WM  = 4 / WN;
    constexpr int MR  = 128 / WM;
    constexpr int FM  = MR / 32;
    constexpr int K   = NKT * 16;
    constexpr int BOFF = 4096;
    constexpr int BUFU = 4096 + 4 * BN * 8;
    constexpr int NIB = BN / 64;
    constexpr int GPI = 2 + NIB;

    __shared__ __align__(16) unsigned short lds[3][BUFU];

    const int tid  = threadIdx.x;
    const int wid  = tid >> 6;
    const int lane = tid & 63;
    const int l31  = lane & 31;
    const int lh   = lane >> 5;
    const int wm   = wid / WN;
    const int wn   = wid % WN;
    const int row0 = blockIdx.y * 128;
    const int n0   = blockIdx.x * BN;

    f32x16 acc[FM][4];
#pragma unroll
    for (int m = 0; m < FM; ++m)
#pragma unroll
        for (int n = 0; n < 4; ++n) acc[m][n] = (f32x16)(0.0f);

    auto stageB = [&](int buf, int kt) {
        const unsigned short* img = Wsp + (size_t)kt * 4 * N * 8;
        unsigned short* dstb = &lds[buf][BOFF];
#pragma unroll
        for (int t = 0; t < NIB; ++t) {
            int e = (wid * NIB + t) * 64 + lane;
            int u = (BN == 256) ? (e >> 8) : (e >> 7);
            int c = e & (BN - 1);
            gll16(img + ((size_t)u * N + n0 + c) * 8, dstb + (size_t)e * 8);
        }
    };
    auto stageA = [&](int buf, int kt) {
#pragma unroll
        for (int t = 0; t < 2; ++t) {
            int i = wid * 2 + t;
            int u = i >> 1, rh = i & 1;
            int row = rh * 64 + lane;
            gll16(Ain + (size_t)(row0 + row) * (2 * K) + kt * 32 + u * 8,
                  &lds[buf][(size_t)i * 512 + (size_t)lane * 8]);
        }
    };
    auto compute = [&](int buf) {
        const unsigned short* Ab = &lds[buf][0];
        const unsigned short* Bb = &lds[buf][BOFF];
        half8 Ah[FM], Al[FM];
#pragma unroll
        for (int fm = 0; fm < FM; ++fm) {
            int row = wm * MR + fm * 32 + l31;
            Ah[fm] = *reinterpret_cast<const half8*>(Ab + (size_t)lh * 1024 + (size_t)row * 8);
            Al[fm] = *reinterpret_cast<const half8*>(Ab + (size_t)(2 + lh) * 1024 + (size_t)row * 8);
        }
#pragma unroll
        for (int nt = 0; nt < 4; ++nt) {
            int col = wn * 128 + nt * 32 + l31;
            half8 Bh = *reinterpret_cast<const half8*>(Bb + (size_t)lh * BN * 8 + (size_t)col * 8);
            half8 Bl = *reinterpret_cast<const half8*>(Bb + (size_t)(2 + lh) * BN * 8 + (size_t)col * 8);
#pragma unroll
            for (int fm = 0; fm < FM; ++fm) {
                acc[fm][nt] = __builtin_amdgcn_mfma_f32_32x32x16_f16(Ah[fm], Bh, acc[fm][nt], 0, 0, 0);
                acc[fm][nt] = __builtin_amdgcn_mfma_f32_32x32x16_f16(Ah[fm], Bl, acc[fm][nt], 0, 0, 0);
                acc[fm][nt] = __builtin_amdgcn_mfma_f32_32x32x16_f16(Al[fm], Bh, acc[fm][nt], 0, 0, 0);
            }
        }
    };

    stageA(0, 0); stageB(0, 0);
    stageA(1, 1); stageB(1, 1);
    waitvm<GPI>();
    barrier_raw();
    for (int kt = 0; kt < NKT; ++kt) {
        const int cur = kt % 3;
        if (kt + 2 < NKT) { const int nb = (kt + 2) % 3; stageA(nb, kt + 2); stageB(nb, kt + 2); }
        compute(cur);
        if (kt < NKT - 2) waitvm<GPI>(); else waitvm<0>();
        barrier_raw();
    }

    if constexpr (OMODE == 0) {
        unsigned short* o = (unsigned short*)Cout;
        const size_t rs = (size_t)N * 2;
#pragma unroll
        for (int fm = 0; fm < FM; ++fm) {
#pragma unroll
            for (int nt = 0; nt < 4; ++nt) {
                const int col = n0 + wn * 128 + nt * 32 + l31;
                const float b = bias[col];
                const size_t cbo = (size_t)(col >> 4) * 32 + (size_t)((col >> 3) & 1) * 8 + (col & 7);
#pragma unroll
                for (int rg = 0; rg < 16; ++rg) {
                    const int row = row0 + wm * MR + fm * 32 + (rg & 3) + 8 * (rg >> 2) + 4 * lh;
                    float v = acc[fm][nt][rg] + b;
                    if (RELU) v = v > 0.f ? v : 0.f;
                    _Float16 hv = (_Float16)v;
                    _Float16 lv = (_Float16)(v - (float)hv);
                    union { _Float16 f; unsigned short u; } ch, cl;
                    ch.f = hv; cl.f = lv;
                    o[(size_t)row * rs + cbo]      = ch.u;
                    o[(size_t)row * rs + cbo + 16] = cl.u;
                }
            }
        }
    } else {
        float* C = (float*)Cout;
        float lacc = 0.f;
#pragma unroll
        for (int fm = 0; fm < FM; ++fm) {
#pragma unroll
            for (int nt = 0; nt < 4; ++nt) {
                const int col = n0 + wn * 128 + nt * 32 + l31;
                const float b = bias[col];
#pragma unroll
                for (int rg = 0; rg < 16; ++rg) {
                    const int row = row0 + wm * MR + fm * 32 + (rg & 3) + 8 * (rg >> 2) + 4 * lh;
                    float v = acc[fm][nt][rg] + b;
                    if (RELU) v = v > 0.f ? v : 0.f;
                    C[(size_t)row * N + col] = v;
                    float d = v - X[(size_t)row * N + col];
                    lacc = fmaf(d, d, lacc);
                }
            }
        }
        __shared__ float red[256];
        red[tid] = lacc;
        __syncthreads();
        for (int s = 128; s > 0; s >>= 1) {
            if (tid < s) red[tid] += red[tid + s];
            __syncthreads();
        }
        if (tid == 0) lossP[blockIdx.y * gridDim.x + blockIdx.x] = red[0];
    }
}

// ---------------------------------------------------------------------------
// Fused residual VQ: all 4 stages in one kernel, residual resident in LDS.
// Block = 64 rows, 512 threads (8 waves: 2 row-halves x 4 code-quarters).
// LDS residual layout: res[kt 32][u 4][row 64][8 u16]  (128 KB)
//   u: 0=h k0..7, 1=h k8..15, 2=l k0..7, 3=l k8..15  (same as act format)
// Score K-loop has NO barriers: res read-only, B streamed from L2-resident
// split codebook via per-wave global loads (compiler-pipelined, full unroll).
// ---------------------------------------------------------------------------
__global__ __launch_bounds__(512, 1)
void vq_fused(const unsigned short* __restrict__ zs,    // z split [B][1024 u16]
              unsigned short* __restrict__ qout,         // quant split out
              const unsigned short* __restrict__ cbs,    // split codebook
              const float* __restrict__ cb,              // f32 codebook
              const float* __restrict__ cnorm,
              float* __restrict__ idx_out,
              float* __restrict__ commitP)
{
    __shared__ __align__(16) unsigned short res[65536];  // 128 KB
    __shared__ float sval[4][64];
    __shared__ int   sidx[4][64];
    __shared__ int   idxbuf[64];
    __shared__ float red[512];

    const int tid  = threadIdx.x;
    const int wid  = tid >> 6;      // 0..7
    const int lane = tid & 63;
    const int l31  = lane & 31;
    const int lh   = lane >> 5;
    const int wm   = wid >> 2;      // 0..1 : row half (32 rows)
    const int wn   = wid & 3;       // 0..3 : code quarter (64 codes)
    const int row0 = blockIdx.x * 64;

    // ---- stage z -> res (global_load_lds; per-lane gather src, linear dst) ----
#pragma unroll
    for (int t = 0; t < 16; ++t) {
        const int unit = wid * 16 + t;          // 0..127 = (kt, u)
        const int kt = unit >> 2, u = unit & 3;
        gll16(zs + (size_t)(row0 + lane) * 1024 + kt * 32 + u * 8,
              res + (size_t)(kt * 4 + u) * 512 + (size_t)lane * 8);
    }
    __syncthreads();                            // implicit vmcnt(0) covers gll

    const half8* c8 = reinterpret_cast<const half8*>(cbs);
    float ca = 0.f;

    for (int q = 0; q < NQ; ++q) {
        const size_t qbase = (size_t)q * 32 * 1024;   // half8 units
        const float* cn = cnorm + q * NCODE;

        // ---- score GEMM: rows (wm) x codes (wn), no barriers ----
        f32x16 acc[2];
        acc[0] = (f32x16)(0.0f);
        acc[1] = (f32x16)(0.0f);
#pragma unroll
        for (int kt = 0; kt < 32; ++kt) {
            const unsigned short* Ab = res + (size_t)(kt * 4 + lh) * 512
                                           + (size_t)(wm * 32 + l31) * 8;
            half8 Ah = *reinterpret_cast<const half8*>(Ab);
            half8 Al = *reinterpret_cast<const half8*>(Ab + 1024);   // u+2
            const size_t eh = qbase + (size_t)kt * 1024 + (size_t)lh * 256;
#pragma unroll
            for (int nt = 0; nt < 2; ++nt) {
                const int code = wn * 64 + nt * 32 + l31;
                half8 Bh = c8[eh + code];
                half8 Bl = c8[eh + 512 + code];
                acc[nt] = __builtin_amdgcn_mfma_f32_32x32x16_f16(Ah, Bh, acc[nt], 0, 0, 0);
                acc[nt] = __builtin_amdgcn_mfma_f32_32x32x16_f16(Ah, Bl, acc[nt], 0, 0, 0);
                acc[nt] = __builtin_amdgcn_mfma_f32_32x32x16_f16(Al, Bh, acc[nt], 0, 0, 0);
            }
        }

        // ---- per-row argmax (first-max tie-break) ----
#pragma unroll
        for (int rg = 0; rg < 16; ++rg) {
            float bv = -FLT_MAX;
            int   bi = 0;
#pragma unroll
            for (int nt = 0; nt < 2; ++nt) {
                const int code = wn * 64 + nt * 32 + l31;
                float s = 2.f * acc[nt][rg] - cn[code];
                if (s > bv || (s == bv && code < bi)) { bv = s; bi = code; }
            }
#pragma unroll
            for (int m = 1; m < 32; m <<= 1) {
                float ov = __shfl_xor(bv, m, 64);
                int   oi = __shfl_xor(bi, m, 64);
                if (ov > bv || (ov == bv && oi < bi)) { bv = ov; bi = oi; }
            }
            if (l31 == 0) {
                const int row = wm * 32 + (rg & 3) + 8 * (rg >> 2) + 4 * lh;
                sval[wn][row] = bv;
                sidx[wn][row] = bi;
            }
        }
        __syncthreads();
        if (tid < 64) {
            float bv = sval[0][tid];
            int   bi = sidx[0][tid];
#pragma unroll
            for (int w = 1; w < 4; ++w) {
                float v = sval[w][tid];
                int   i = sidx[w][tid];
                if (v > bv || (v == bv && i < bi)) { bv = v; bi = i; }
            }
            idxbuf[tid] = bi;
            idx_out[(size_t)(row0 + tid) * NQ + q] = (float)bi;
        }
        __syncthreads();

        // ---- residual update in LDS (lane = row; conflict-free) ----
#pragma unroll
        for (int t = 0; t < 8; ++t) {
            const int pair = wid * 8 + t;       // 0..63 = (kt, kh)
            const int kt = pair >> 1, kh = pair & 1;
            const size_t rb = (size_t)(kt * 4 + kh) * 512 + (size_t)lane * 8;
            half8 rh = *reinterpret_cast<const half8*>(res + rb);
            half8 rl = *reinterpret_cast<const half8*>(res + rb + 1024);
            const float* crow = cb + ((size_t)(q * NCODE + idxbuf[lane])) * HDIM
                                   + kt * 16 + kh * 8;
            float4 c0 = *reinterpret_cast<const float4*>(crow);
            float4 c1 = *reinterpret_cast<const float4*>(crow + 4);
            float cv[8] = {c0.x, c0.y, c0.z, c0.w, c1.x, c1.y, c1.z, c1.w};
            float d[8];
#pragma unroll
            for (int e = 0; e < 8; ++e) {
                float rv = (float)rh[e] + (float)rl[e];
                d[e] = rv - cv[e];
                ca = fmaf(d[e], d[e], ca);
            }
            if (q < NQ - 1) {
                half8 oh, ol;
                cvt_hl8(d, oh, ol);
                *reinterpret_cast<half8*>(res + rb)        = oh;
                *reinterpret_cast<half8*>(res + rb + 1024) = ol;
            } else {
                // quant = z - d (z from global split; L3-resident)
                const unsigned short* zp = zs + (size_t)(row0 + lane) * 1024
                                              + kt * 32 + kh * 8;
                half8 zh = *reinterpret_cast<const half8*>(zp);
                half8 zl = *reinterpret_cast<const half8*>(zp + 16);
                float qv[8];
#pragma unroll
                for (int e = 0; e < 8; ++e)
                    qv[e] = ((float)zh[e] + (float)zl[e]) - d[e];
                half8 oh, ol;
                cvt_hl8(qv, oh, ol);
                unsigned short* op = qout + (size_t)(row0 + lane) * 1024
                                          + kt * 32 + kh * 8;
                *reinterpret_cast<half8*>(op)      = oh;
                *reinterpret_cast<half8*>(op + 16) = ol;
            }
        }
        __syncthreads();
    }

    // ---- commit partial (summed over all 4 stages) ----
    red[tid] = ca;
    __syncthreads();
    for (int s = 256; s > 0; s >>= 1) {
        if (tid < s) red[tid] += red[tid + s];
        __syncthreads();
    }
    if (tid == 0) commitP[blockIdx.x] = red[0];
}

// ---------------------------------------------------------------------------
__global__ __launch_bounds__(256)
void loss_reduce(const float* __restrict__ cP, int nc,
                 const float* __restrict__ rP, int nr,
                 float* __restrict__ out2)
{
    __shared__ float red[256];
    const int tid = threadIdx.x;

    float s = 0.f;
    for (int i = tid; i < nc; i += 256) s += cP[i];
    red[tid] = s;
    __syncthreads();
    for (int st = 128; st > 0; st >>= 1) {
        if (tid < st) red[tid] += red[tid + st];
        __syncthreads();
    }
    float ctot = red[0];
    __syncthreads();

    s = 0.f;
    for (int i = tid; i < nr; i += 256) s += rP[i];
    red[tid] = s;
    __syncthreads();
    for (int st = 128; st > 0; st >>= 1) {
        if (tid < st) red[tid] += red[tid + st];
        __syncthreads();
    }
    if (tid == 0) {
        out2[0] = red[0] / ((float)BATCH * (float)EDIM);
        out2[1] = 0.25f * ctot / ((float)BATCH * (float)HDIM);
    }
}

// ---------------------------------------------------------------------------
extern "C" void kernel_launch(void* const* d_in, const int* in_sizes, int n_in,
                              void* d_out, int out_size, void* d_ws, size_t ws_size,
                              hipStream_t stream)
{
    const float* x   = (const float*)d_in[0];
    const float* ew1 = (const float*)d_in[1];
    const float* eb1 = (const float*)d_in[2];
    const float* ew2 = (const float*)d_in[3];
    const float* eb2 = (const float*)d_in[4];
    const float* cb  = (const float*)d_in[5];
    const float* dw1 = (const float*)d_in[6];
    const float* db1 = (const float*)d_in[7];
    const float* dw2 = (const float*)d_in[8];
    const float* db2 = (const float*)d_in[9];

    float* out = (float*)d_out;
    float* ws  = (float*)d_ws;
    unsigned short* P0  = (unsigned short*)(ws + WS_P0);
    unsigned short* P1  = (unsigned short*)(ws + WS_P1);
    unsigned short* XS  = P1;                    // x-split aliased into P1
    unsigned short* cbs = (unsigned short*)(ws + WS_CBSPL);
    float* cn = ws + WS_CNORM;
    float* cP = ws + WS_COMMITP;
    float* rP = ws + WS_RECONP;
    unsigned short* w1s = (unsigned short*)(ws + WS_W1S);
    unsigned short* w2s = (unsigned short*)(ws + WS_W2S);
    unsigned short* w3s = (unsigned short*)(ws + WS_W3S);
    unsigned short* w4s = (unsigned short*)(ws + WS_W4S);

    // prep
    cnorm_kernel<<<NQ * NCODE, 64, 0, stream>>>(cb, cn);
    split_cb<<<256, 256, 0, stream>>>(cb, cbs);
    split_x<<<BATCH * 48 / 256, 256, 0, stream>>>(x, XS);
    split_w<<<(EDIM / 16) * 2 * HDIM / 256, 256, 0, stream>>>(ew1, w1s, HDIM, EDIM);
    split_w<<<(HDIM / 16) * 2 * HDIM / 256, 256, 0, stream>>>(ew2, w2s, HDIM, HDIM);
    split_w<<<(HDIM / 16) * 2 * HDIM / 256, 256, 0, stream>>>(dw1, w3s, HDIM, HDIM);
    split_w<<<(HDIM / 16) * 2 * EDIM / 256, 256, 0, stream>>>(dw2, w4s, EDIM, HDIM);

    // encoder: x-split (in P1) -> h1-split (P0) -> z-split (P1)
    gemm_pl<256, 24, 0, true><<<dim3(HDIM / 256, BATCH / 128), 256, 0, stream>>>(
        XS, w1s, eb1, P0, nullptr, nullptr, HDIM);
    gemm_pl<256, 32, 0, false><<<dim3(HDIM / 256, BATCH / 128), 256, 0, stream>>>(
        P0, w2s, eb2, P1, nullptr, nullptr, HDIM);

    // fused residual VQ: z (P1) -> quant-split (P0), indices, commit partials
    float* idxo = out + OUT_IDX_OFF;
    vq_fused<<<BATCH / 64, 512, 0, stream>>>(P1, P0, cbs, cb, cn, idxo, cP);

    // decoder: quant (P0) -> hidden (P1) -> recon (out) + loss
    gemm_pl<256, 32, 0, true><<<dim3(HDIM / 256, BATCH / 128), 256, 0, stream>>>(
        P0, w3s, db1, P1, nullptr, nullptr, HDIM);
    gemm_pl<128, 32, 1, false><<<dim3(EDIM / 128, BATCH / 128), 256, 0, stream>>>(
        P1, w4s, db2, out, x, rP, EDIM);

    // losses
    loss_reduce<<<1, 256, 0, stream>>>(cP, BATCH / 64, rP,
                                       (BATCH / 128) * (EDIM / 128),
                                       out + OUT_RL_OFF);
}

// Round 9
// 996.118 us; speedup vs baseline: 1.1596x; 1.1596x over previous
//
#include <hip/hip_runtime.h>
#include <cfloat>
#include <cstddef>
#include <cstdint>

// ---------------------------------------------------------------------------
// SemanticRQVAE forward, round 9: Gram-matrix VQ reformulation.
//   scores_q = 2*(z.c_j - sum_{p<q} G[p][q][i_p][j]) - |c_j|^2
//   |r_{q+1}|^2 = |r_q|^2 - s*_q   (s* = maximized score)  -> commit scalar
//   quantized  = sum of chosen code vectors (straight-through value)
// VQ = 4x {GEMM z.CB^T + fused argmax epilogue} + rownorm + gather-sum.
// GEMM pipeline (counted-vmcnt, global_load_lds 3-ring) proven in R6/R7.
// Activation format, per row, per k-tile of 16 (64 B):
//   [u=0] h(k0..7) [u=1] h(k8..15) [u=2] l(k0..7) [u=3] l(k8..15)
// d_out layout (floats): recon | indices-as-float | recon_loss | commit_loss
// ---------------------------------------------------------------------------

#define BATCH   65536
#define EDIM    384
#define HDIM    512
#define NCODE   256
#define NQ      4

#define OUT_IDX_OFF 25165824
#define OUT_RL_OFF  25427968
#define WS_P0       0
#define WS_P1       33554432
#define WS_CBW      67108864     // 524288 fl (w-split of all 1024 codes, N=1024)
#define WS_CNORM    67633152
#define WS_COMMITP  67634176
#define WS_RECONP   67636224
#define WS_W1S      67637760
#define WS_W2S      67834368
#define WS_W3S      68096512
#define WS_W4S      68358656     // ends 68555264
#define WS_CBA      68555264     // 524288 fl (act-split of 1024 code rows)
#define WS_G6       69079552     // 393216 fl (6 x 256 x 256)
#define WS_ZN       69472768     // 65536
#define WS_SSTAR    69538304     // 262144 ([q][65536])
#define WS_IDXI     69800448     // 262144 int ([q][65536])

typedef _Float16 half8 __attribute__((ext_vector_type(8)));
typedef float    f32x16 __attribute__((ext_vector_type(16)));

__device__ __forceinline__ void cvt_hl8(const float* vs, half8& h, half8& l)
{
#pragma unroll
    for (int j = 0; j < 8; ++j) {
        _Float16 hv = (_Float16)vs[j];
        h[j] = hv;
        l[j] = (_Float16)(vs[j] - (float)hv);
    }
}

__device__ __forceinline__ void gll16(const unsigned short* g, unsigned short* l)
{
    __builtin_amdgcn_global_load_lds(
        (const __attribute__((address_space(1))) unsigned int*)g,
        (__attribute__((address_space(3))) unsigned int*)l, 16, 0, 0);
}

template <int N> __device__ __forceinline__ void waitvm()
{
    __builtin_amdgcn_sched_barrier(0);
    if constexpr (N == 0)      asm volatile("s_waitcnt vmcnt(0)" ::: "memory");
    else if constexpr (N == 6) asm volatile("s_waitcnt vmcnt(6)" ::: "memory");
    __builtin_amdgcn_sched_barrier(0);
}
__device__ __forceinline__ void barrier_raw()
{
    __builtin_amdgcn_s_barrier();
    __builtin_amdgcn_sched_barrier(0);
}

// ---------------------------------------------------------------------------
// One-shot splits
// ---------------------------------------------------------------------------
// generic activation split: src [rows][K] f32 -> act-format u16 (row stride 2K)
__global__ __launch_bounds__(256)
void split_act(const float* __restrict__ src, unsigned short* __restrict__ dst,
               int K)
{
    int u = blockIdx.x * 256 + threadIdx.x;       // rows * (K/8) units
    int upr = K >> 3;
    int row = u / upr;
    int rem = u % upr;
    int kt = rem >> 1, kh = rem & 1;
    const float* p = src + (size_t)row * K + kt * 16 + kh * 8;
    float vs[8];
#pragma unroll
    for (int j = 0; j < 8; ++j) vs[j] = p[j];
    half8 h, l;
    cvt_hl8(vs, h, l);
    unsigned short* o = dst + (size_t)row * (2 * K) + kt * 32 + kh * 8;
    *reinterpret_cast<half8*>(o)      = h;
    *reinterpret_cast<half8*>(o + 16) = l;
}

__global__ __launch_bounds__(256)
void split_w(const float* __restrict__ W, unsigned short* __restrict__ out,
             int N, int K)
{
    int u = blockIdx.x * 256 + threadIdx.x;
    int col  = u % N;
    int rem  = u / N;
    int khalf = rem & 1;
    int kt    = rem >> 1;
    int kbase = kt * 16 + khalf * 8;
    float vs[8];
#pragma unroll
    for (int j = 0; j < 8; ++j) vs[j] = W[(size_t)(kbase + j) * N + col];
    half8 h, l;
    cvt_hl8(vs, h, l);
    *reinterpret_cast<half8*>(out + ((size_t)(kt * 4 + khalf) * N + col) * 8)     = h;
    *reinterpret_cast<half8*>(out + ((size_t)(kt * 4 + 2 + khalf) * N + col) * 8) = l;
}

// codebook as weight: W[k][n] = cb[n][k], N = 1024, K = 512
__global__ __launch_bounds__(256)
void split_cbw(const float* __restrict__ cb, unsigned short* __restrict__ out)
{
    int u = blockIdx.x * 256 + threadIdx.x;        // 65536 = 32kt x 2kh x 1024col
    int col = u & 1023;
    int rem = u >> 10;
    int kh = rem & 1;
    int kt = rem >> 1;
    const float* p = cb + (size_t)col * HDIM + kt * 16 + kh * 8;
    float vs[8];
#pragma unroll
    for (int j = 0; j < 8; ++j) vs[j] = p[j];
    half8 h, l;
    cvt_hl8(vs, h, l);
    *reinterpret_cast<half8*>(out + ((size_t)(kt * 4 + kh) * 1024 + col) * 8)     = h;
    *reinterpret_cast<half8*>(out + ((size_t)(kt * 4 + 2 + kh) * 1024 + col) * 8) = l;
}

__global__ __launch_bounds__(64)
void cnorm_kernel(const float* __restrict__ cb, float* __restrict__ cnorm)
{
    const int code = blockIdx.x;
    const int lane = threadIdx.x;
    const float* r = cb + (size_t)code * HDIM;
    float s = 0.f;
    for (int k = lane; k < HDIM; k += 64) s = fmaf(r[k], r[k], s);
#pragma unroll
    for (int off = 32; off > 0; off >>= 1) s += __shfl_down(s, off);
    if (lane == 0) cnorm[code] = s;
}

// |z|^2 per row from split storage (value of z IS h+l by construction)
__global__ __launch_bounds__(256)
void rownorm(const unsigned short* __restrict__ zs, float* __restrict__ zn)
{
    const int tid = threadIdx.x, wid = tid >> 6, lane = tid & 63;
    const int row = blockIdx.x * 4 + wid;
    const unsigned short* p = zs + (size_t)row * 1024
                                 + (lane >> 1) * 32 + (lane & 1) * 8;
    half8 h = *reinterpret_cast<const half8*>(p);
    half8 l = *reinterpret_cast<const half8*>(p + 16);
    float s = 0.f;
#pragma unroll
    for (int e = 0; e < 8; ++e) {
        float v = (float)h[e] + (float)l[e];
        s = fmaf(v, v, s);
    }
#pragma unroll
    for (int off = 32; off > 0; off >>= 1) s += __shfl_down(s, off);
    if (lane == 0) zn[row] = s;
}

// ---------------------------------------------------------------------------
// Pipelined MFMA GEMM (R6-proven). OMODE 0: split-act out; 1: f32 + loss;
// 2: raw f32 out with ldc=256, no bias (Gram).
// ---------------------------------------------------------------------------
template <int BN, int NKT, int OMODE, bool RELU>
__global__ __launch_bounds__(256, 2)
void gemm_pl(const unsigned short* __restrict__ Ain,
             const unsigned short* __restrict__ Wsp,
             const float* __restrict__ bias, void* __restrict__ Cout,
             const float* __restrict__ X, float* __restrict__ lossP, int N)
{
    constexpr int WN  = BN / 128;
    constexpr int WM  = 4 / WN;
    constexpr int MR  = 128 / WM;
    constexpr int FM  = MR / 32;
    constexpr int K   = NKT * 16;
    constexpr int BOFF = 4096;
    constexpr int BUFU = 4096 + 4 * BN * 8;
    constexpr int NIB = BN / 64;

    __shared__ __align__(16) unsigned short lds[3][BUFU];

    const int tid  = threadIdx.x;
    const int wid  = tid >> 6;
    const int lane = tid & 63;
    const int l31  = lane & 31;
    const int lh   = lane >> 5;
    const int wm   = wid / WN;
    const int wn   = wid % WN;
    const int row0 = blockIdx.y * 128;
    const int n0   = blockIdx.x * BN;

    f32x16 acc[FM][4];
#pragma unroll
    for (int m = 0; m < FM; ++m)
#pragma unroll
        for (int n = 0; n < 4; ++n) acc[m][n] = (f32x16)(0.0f);

    auto stageB = [&](int buf, int kt) {
        const unsigned short* img = Wsp + (size_t)kt * 4 * N * 8;
        unsigned short* dstb = &lds[buf][BOFF];
#pragma unroll
        for (int t = 0; t < NIB; ++t) {
            int e = (wid * NIB + t) * 64 + lane;
            int u = (BN == 256) ? (e >> 8) : (e >> 7);
            int c = e & (BN - 1);
            gll16(img + ((size_t)u * N + n0 + c) * 8, dstb + (size_t)e * 8);
        }
    };
    auto stageA = [&](int buf, int kt) {
#pragma unroll
        for (int t = 0; t < 2; ++t) {
            int i = wid * 2 + t;
            int u = i >> 1, rh = i & 1;
            int row = rh * 64 + lane;
            gll16(Ain + (size_t)(row0 + row) * (2 * K) + kt * 32 + u * 8,
                  &lds[buf][(size_t)i * 512 + (size_t)lane * 8]);
        }
    };
    auto compute = [&](int buf) {
        const unsigned short* Ab = &lds[buf][0];
        const unsigned short* Bb = &lds[buf][BOFF];
        half8 Ah[FM], Al[FM];
#pragma unroll
        for (int fm = 0; fm < FM; ++fm) {
            int row = wm * MR + fm * 32 + l31;
            Ah[fm] = *reinterpret_cast<const half8*>(Ab + (size_t)lh * 1024 + (size_t)row * 8);
            Al[fm] = *reinterpret_cast<const half8*>(Ab + (size_t)(2 + lh) * 1024 + (size_t)row * 8);
        }
#pragma unroll
        for (int nt = 0; nt < 4; ++nt) {
            int col = wn * 128 + nt * 32 + l31;
            half8 Bh = *reinterpret_cast<const half8*>(Bb + (size_t)lh * BN * 8 + (size_t)col * 8);
            half8 Bl = *reinterpret_cast<const half8*>(Bb + (size_t)(2 + lh) * BN * 8 + (size_t)col * 8);
#pragma unroll
            for (int fm = 0; fm < FM; ++fm) {
                acc[fm][nt] = __builtin_amdgcn_mfma_f32_32x32x16_f16(Ah[fm], Bh, acc[fm][nt], 0, 0, 0);
                acc[fm][nt] = __builtin_amdgcn_mfma_f32_32x32x16_f16(Ah[fm], Bl, acc[fm][nt], 0, 0, 0);
                acc[fm][nt] = __builtin_amdgcn_mfma_f32_32x32x16_f16(Al[fm], Bh, acc[fm][nt], 0, 0, 0);
            }
        }
    };

    stageA(0, 0); stageB(0, 0);
    stageA(1, 1); stageB(1, 1);
    waitvm<6>();
    barrier_raw();
    for (int kt = 0; kt < NKT; ++kt) {
        const int cur = kt % 3;
        if (kt + 2 < NKT) { const int nb = (kt + 2) % 3; stageA(nb, kt + 2); stageB(nb, kt + 2); }
        compute(cur);
        if (kt < NKT - 2) waitvm<6>(); else waitvm<0>();
        barrier_raw();
    }

    if constexpr (OMODE == 0) {
        unsigned short* o = (unsigned short*)Cout;
        const size_t rs = (size_t)N * 2;
#pragma unroll
        for (int fm = 0; fm < FM; ++fm) {
#pragma unroll
            for (int nt = 0; nt < 4; ++nt) {
                const int col = n0 + wn * 128 + nt * 32 + l31;
                const float b = bias[col];
                const size_t cbo = (size_t)(col >> 4) * 32 + (size_t)((col >> 3) & 1) * 8 + (col & 7);
#pragma unroll
                for (int rg = 0; rg < 16; ++rg) {
                    const int row = row0 + wm * MR + fm * 32 + (rg & 3) + 8 * (rg >> 2) + 4 * lh;
                    float v = acc[fm][nt][rg] + b;
                    if (RELU) v = v > 0.f ? v : 0.f;
                    _Float16 hv = (_Float16)v;
                    _Float16 lv = (_Float16)(v - (float)hv);
                    union { _Float16 f; unsigned short u; } ch, cl;
                    ch.f = hv; cl.f = lv;
                    o[(size_t)row * rs + cbo]      = ch.u;
                    o[(size_t)row * rs + cbo + 16] = cl.u;
                }
            }
        }
    } else if constexpr (OMODE == 1) {
        float* C = (float*)Cout;
        float lacc = 0.f;
#pragma unroll
        for (int fm = 0; fm < FM; ++fm) {
#pragma unroll
            for (int nt = 0; nt < 4; ++nt) {
                const int col = n0 + wn * 128 + nt * 32 + l31;
                const float b = bias[col];
#pragma unroll
                for (int rg = 0; rg < 16; ++rg) {
                    const int row = row0 + wm * MR + fm * 32 + (rg & 3) + 8 * (rg >> 2) + 4 * lh;
                    float v = acc[fm][nt][rg] + b;
                    if (RELU) v = v > 0.f ? v : 0.f;
                    C[(size_t)row * N + col] = v;
                    float d = v - X[(size_t)row * N + col];
                    lacc = fmaf(d, d, lacc);
                }
            }
        }
        __shared__ float red[256];
        red[tid] = lacc;
        __syncthreads();
        for (int s = 128; s > 0; s >>= 1) {
            if (tid < s) red[tid] += red[tid + s];
            __syncthreads();
        }
        if (tid == 0) lossP[blockIdx.y * gridDim.x + blockIdx.x] = red[0];
    } else {
        // OMODE 2: raw f32, ldc = 256, no bias (Gram blocks)
        float* C = (float*)Cout;
#pragma unroll
        for (int fm = 0; fm < FM; ++fm) {
#pragma unroll
            for (int nt = 0; nt < 4; ++nt) {
                const int col = wn * 128 + nt * 32 + l31;
#pragma unroll
                for (int rg = 0; rg < 16; ++rg) {
                    const int row = row0 + wm * MR + fm * 32 + (rg & 3) + 8 * (rg >> 2) + 4 * lh;
                    C[(size_t)row * 256 + col] = acc[fm][nt][rg];
                }
            }
        }
    }
}

// ---------------------------------------------------------------------------
// VQ score stage Q: GEMM (z . CB_Q^T) with Gram-corrected argmax epilogue.
// Block 128 rows x 256 codes, 4 waves (2x2). Writes idx (float + int) and
// s* (best adjusted score) per row. No residual anywhere.
// ---------------------------------------------------------------------------
template <int Q>
__global__ __launch_bounds__(256, 2)
void vq_score(const unsigned short* __restrict__ zs,
              const unsigned short* __restrict__ cbw,   // N=1024 w-split
              const float* __restrict__ G6,             // [6][256][256]
              const float* __restrict__ cnorm,
              float* __restrict__ idx_out,
              int* __restrict__ idxi,
              float* __restrict__ sstar)
{
    constexpr int NKT = 32;
    constexpr int N   = 1024;
    __shared__ __align__(16) unsigned short lds[3][12288];
    __shared__ float sval[2][128];
    __shared__ int   sidx[2][128];

    const int tid  = threadIdx.x;
    const int wid  = tid >> 6;
    const int lane = tid & 63;
    const int l31  = lane & 31;
    const int lh   = lane >> 5;
    const int wm   = wid >> 1;
    const int wn   = wid & 1;
    const int row0 = blockIdx.x * 128;
    const int n0   = Q * 256;

    f32x16 acc[2][4];
#pragma unroll
    for (int m = 0; m < 2; ++m)
#pragma unroll
        for (int n = 0; n < 4; ++n) acc[m][n] = (f32x16)(0.0f);

    auto stageB = [&](int buf, int kt) {
        const unsigned short* img = cbw + (size_t)kt * 4 * N * 8;
        unsigned short* dstb = &lds[buf][4096];
#pragma unroll
        for (int t = 0; t < 4; ++t) {
            int e = (wid * 4 + t) * 64 + lane;
            int u = e >> 8;
            int c = e & 255;
            gll16(img + ((size_t)u * N + n0 + c) * 8, dstb + (size_t)e * 8);
        }
    };
    auto stageA = [&](int buf, int kt) {
#pragma unroll
        for (int t = 0; t < 2; ++t) {
            int i = wid * 2 + t;
            int u = i >> 1, rh = i & 1;
            int row = rh * 64 + lane;
            gll16(zs + (size_t)(row0 + row) * 1024 + kt * 32 + u * 8,
                  &lds[buf][(size_t)i * 512 + (size_t)lane * 8]);
        }
    };
    auto compute = [&](int buf) {
        const unsigned short* Ab = &lds[buf][0];
        const unsigned short* Bb = &lds[buf][4096];
        half8 Ah[2], Al[2];
#pragma unroll
        for (int fm = 0; fm < 2; ++fm) {
            int row = wm * 64 + fm * 32 + l31;
            Ah[fm] = *reinterpret_cast<const half8*>(Ab + (size_t)lh * 1024 + (size_t)row * 8);
            Al[fm] = *reinterpret_cast<const half8*>(Ab + (size_t)(2 + lh) * 1024 + (size_t)row * 8);
        }
#pragma unroll
        for (int nt = 0; nt < 4; ++nt) {
            int col = wn * 128 + nt * 32 + l31;
            half8 Bh = *reinterpret_cast<const half8*>(Bb + (size_t)lh * 2048 + (size_t)col * 8);
            half8 Bl = *reinterpret_cast<const half8*>(Bb + (size_t)(2 + lh) * 2048 + (size_t)col * 8);
#pragma unroll
            for (int fm = 0; fm < 2; ++fm) {
                acc[fm][nt] = __builtin_amdgcn_mfma_f32_32x32x16_f16(Ah[fm], Bh, acc[fm][nt], 0, 0, 0);
                acc[fm][nt] = __builtin_amdgcn_mfma_f32_32x32x16_f16(Ah[fm], Bl, acc[fm][nt], 0, 0, 0);
                acc[fm][nt] = __builtin_amdgcn_mfma_f32_32x32x16_f16(Al[fm], Bh, acc[fm][nt], 0, 0, 0);
            }
        }
    };

    stageA(0, 0); stageB(0, 0);
    stageA(1, 1); stageB(1, 1);
    waitvm<6>();
    barrier_raw();
    for (int kt = 0; kt < NKT; ++kt) {
        const int cur = kt % 3;
        if (kt + 2 < NKT) { const int nb = (kt + 2) % 3; stageA(nb, kt + 2); stageB(nb, kt + 2); }
        compute(cur);
        if (kt < NKT - 2) waitvm<6>(); else waitvm<0>();
        barrier_raw();
    }

    // ---- Gram-corrected scores + per-row argmax (first-max tie-break) ----
    const float* cn = cnorm + Q * NCODE;
    // pair indices into G6 for (p, Q), p < Q:
    constexpr int PAIR0 = (Q == 1) ? 0 : (Q == 2) ? 1 : 2;   // (0,Q)
    constexpr int PAIR1 = (Q == 2) ? 3 : 4;                  // (1,Q)
    constexpr int PAIR2 = 5;                                 // (2,3)
#pragma unroll
    for (int fm = 0; fm < 2; ++fm) {
#pragma unroll
        for (int rg = 0; rg < 16; ++rg) {
            const int grow = row0 + wm * 64 + fm * 32 + (rg & 3) + 8 * (rg >> 2) + 4 * lh;
            const float* gr0 = nullptr; const float* gr1 = nullptr; const float* gr2 = nullptr;
            if constexpr (Q > 0) gr0 = G6 + ((size_t)PAIR0 * 256 + idxi[0 * 65536 + grow]) * 256;
            if constexpr (Q > 1) gr1 = G6 + ((size_t)PAIR1 * 256 + idxi[1 * 65536 + grow]) * 256;
            if constexpr (Q > 2) gr2 = G6 + ((size_t)PAIR2 * 256 + idxi[2 * 65536 + grow]) * 256;
            float bv = -FLT_MAX;
            int   bi = 0;
#pragma unroll
            for (int nt = 0; nt < 4; ++nt) {
                const int code = wn * 128 + nt * 32 + l31;
                float a = acc[fm][nt][rg];
                if constexpr (Q > 0) a -= gr0[code];
                if constexpr (Q > 1) a -= gr1[code];
                if constexpr (Q > 2) a -= gr2[code];
                float s = 2.f * a - cn[code];
                if (s > bv || (s == bv && code < bi)) { bv = s; bi = code; }
            }
#pragma unroll
            for (int m = 1; m < 32; m <<= 1) {
                float ov = __shfl_xor(bv, m, 64);
                int   oi = __shfl_xor(bi, m, 64);
                if (ov > bv || (ov == bv && oi < bi)) { bv = ov; bi = oi; }
            }
            if (l31 == 0) {
                const int row = wm * 64 + fm * 32 + (rg & 3) + 8 * (rg >> 2) + 4 * lh;
                sval[wn][row] = bv;
                sidx[wn][row] = bi;
            }
        }
    }
    __syncthreads();
    if (tid < 128) {
        float v0 = sval[0][tid], v1 = sval[1][tid];
        int   i0 = sidx[0][tid], i1 = sidx[1][tid];
        float bv = (v1 > v0 || (v1 == v0 && i1 < i0)) ? v1 : v0;
        int   bi = (v1 > v0 || (v1 == v0 && i1 < i0)) ? i1 : i0;
        const int grow = row0 + tid;
        idxi[Q * 65536 + grow]  = bi;
        sstar[Q * 65536 + grow] = bv;
        idx_out[(size_t)grow * NQ + Q] = (float)bi;
    }
}

// ---------------------------------------------------------------------------
// quant = sum of chosen codes (split-format out) + commit partials.
// commit per row = sum_q |r_{q+1}|^2 with |r_{q+1}|^2 = |r_q|^2 - s*_q.
// ---------------------------------------------------------------------------
__global__ __launch_bounds__(256)
void vq_quant(const int* __restrict__ idxi, const float* __restrict__ sstar,
              const float* __restrict__ zn, const float* __restrict__ cb,
              unsigned short* __restrict__ qout, float* __restrict__ commitP)
{
    __shared__ float red[256];
    const int tid = threadIdx.x, wid = tid >> 6, lane = tid & 63;
    float ca = 0.f;

#pragma unroll
    for (int t = 0; t < 8; ++t) {
        const int row = blockIdx.x * 32 + wid * 8 + t;
        const int i0 = idxi[row],          i1 = idxi[65536 + row];
        const int i2 = idxi[131072 + row], i3 = idxi[196608 + row];
        const int koff = lane * 8;
        const float* c0 = cb + ((size_t)(0 * NCODE + i0)) * HDIM + koff;
        const float* c1 = cb + ((size_t)(1 * NCODE + i1)) * HDIM + koff;
        const float* c2 = cb + ((size_t)(2 * NCODE + i2)) * HDIM + koff;
        const float* c3 = cb + ((size_t)(3 * NCODE + i3)) * HDIM + koff;
        float q[8];
#pragma unroll
        for (int half = 0; half < 2; ++half) {
            float4 v0 = *reinterpret_cast<const float4*>(c0 + half * 4);
            float4 v1 = *reinterpret_cast<const float4*>(c1 + half * 4);
            float4 v2 = *reinterpret_cast<const float4*>(c2 + half * 4);
            float4 v3 = *reinterpret_cast<const float4*>(c3 + half * 4);
            q[half * 4 + 0] = ((v0.x + v1.x) + v2.x) + v3.x;
            q[half * 4 + 1] = ((v0.y + v1.y) + v2.y) + v3.y;
            q[half * 4 + 2] = ((v0.z + v1.z) + v2.z) + v3.z;
            q[half * 4 + 3] = ((v0.w + v1.w) + v2.w) + v3.w;
        }
        half8 oh, ol;
        cvt_hl8(q, oh, ol);
        unsigned short* op = qout + (size_t)row * 1024
                                  + (lane >> 1) * 32 + (lane & 1) * 8;
        *reinterpret_cast<half8*>(op)      = oh;
        *reinterpret_cast<half8*>(op + 16) = ol;

        if (lane == 0) {
            float rn = zn[row];
            rn -= sstar[row];           float cm = rn;
            rn -= sstar[65536 + row];   cm += rn;
            rn -= sstar[131072 + row];  cm += rn;
            rn -= sstar[196608 + row];  cm += rn;
            ca += cm;
        }
    }

    red[tid] = ca;
    __syncthreads();
    for (int s = 128; s > 0; s >>= 1) {
        if (tid < s) red[tid] += red[tid + s];
        __syncthreads();
    }
    if (tid == 0) commitP[blockIdx.x] = red[0];
}

// ---------------------------------------------------------------------------
__global__ __launch_bounds__(256)
void loss_reduce(const float* __restrict__ cP, int nc,
                 const float* __restrict__ rP, int nr,
                 float* __restrict__ out2)
{
    __shared__ float red[256];
    const int tid = threadIdx.x;

    float s = 0.f;
    for (int i = tid; i < nc; i += 256) s += cP[i];
    red[tid] = s;
    __syncthreads();
    for (int st = 128; st > 0; st >>= 1) {
        if (tid < st) red[tid] += red[tid + st];
        __syncthreads();
    }
    float ctot = red[0];
    __syncthreads();

    s = 0.f;
    for (int i = tid; i < nr; i += 256) s += rP[i];
    red[tid] = s;
    __syncthreads();
    for (int st = 128; st > 0; st >>= 1) {
        if (tid < st) red[tid] += red[tid + st];
        __syncthreads();
    }
    if (tid == 0) {
        out2[0] = red[0] / ((float)BATCH * (float)EDIM);
        out2[1] = 0.25f * ctot / ((float)BATCH * (float)HDIM);
    }
}

// ---------------------------------------------------------------------------
extern "C" void kernel_launch(void* const* d_in, const int* in_sizes, int n_in,
                              void* d_out, int out_size, void* d_ws, size_t ws_size,
                              hipStream_t stream)
{
    const float* x   = (const float*)d_in[0];
    const float* ew1 = (const float*)d_in[1];
    const float* eb1 = (const float*)d_in[2];
    const float* ew2 = (const float*)d_in[3];
    const float* eb2 = (const float*)d_in[4];
    const float* cb  = (const float*)d_in[5];
    const float* dw1 = (const float*)d_in[6];
    const float* db1 = (const float*)d_in[7];
    const float* dw2 = (const float*)d_in[8];
    const float* db2 = (const float*)d_in[9];

    float* out = (float*)d_out;
    float* ws  = (float*)d_ws;
    unsigned short* P0  = (unsigned short*)(ws + WS_P0);
    unsigned short* P1  = (unsigned short*)(ws + WS_P1);
    unsigned short* XS  = P1;                    // x-split aliased into P1
    unsigned short* cbw = (unsigned short*)(ws + WS_CBW);
    unsigned short* cba = (unsigned short*)(ws + WS_CBA);
    float* G6 = ws + WS_G6;
    float* zn = ws + WS_ZN;
    float* ss = ws + WS_SSTAR;
    int*   ii = (int*)(ws + WS_IDXI);
    float* cn = ws + WS_CNORM;
    float* cP = ws + WS_COMMITP;
    float* rP = ws + WS_RECONP;
    unsigned short* w1s = (unsigned short*)(ws + WS_W1S);
    unsigned short* w2s = (unsigned short*)(ws + WS_W2S);
    unsigned short* w3s = (unsigned short*)(ws + WS_W3S);
    unsigned short* w4s = (unsigned short*)(ws + WS_W4S);

    // prep: norms + splits
    cnorm_kernel<<<NQ * NCODE, 64, 0, stream>>>(cb, cn);
    split_act<<<BATCH * 48 / 256, 256, 0, stream>>>(x, XS, EDIM);
    split_act<<<1024 * 64 / 256, 256, 0, stream>>>(cb, cba, HDIM);
    split_cbw<<<256, 256, 0, stream>>>(cb, cbw);
    split_w<<<(EDIM / 16) * 2 * HDIM / 256, 256, 0, stream>>>(ew1, w1s, HDIM, EDIM);
    split_w<<<(HDIM / 16) * 2 * HDIM / 256, 256, 0, stream>>>(ew2, w2s, HDIM, HDIM);
    split_w<<<(HDIM / 16) * 2 * HDIM / 256, 256, 0, stream>>>(dw1, w3s, HDIM, HDIM);
    split_w<<<(HDIM / 16) * 2 * EDIM / 256, 256, 0, stream>>>(dw2, w4s, EDIM, HDIM);

    // Gram blocks G6[pair] = C_p . C_q^T  (pairs (0,1),(0,2),(0,3),(1,2),(1,3),(2,3))
    {
        const int pairs[6][2] = {{0,1},{0,2},{0,3},{1,2},{1,3},{2,3}};
        for (int pi = 0; pi < 6; ++pi) {
            const int p = pairs[pi][0], q = pairs[pi][1];
            gemm_pl<256, 32, 2, false><<<dim3(1, 2), 256, 0, stream>>>(
                cba + (size_t)p * 256 * 1024, cbw + (size_t)q * 256 * 8,
                nullptr, G6 + (size_t)pi * 65536, nullptr, nullptr, 1024);
        }
    }

    // encoder: x-split (P1) -> h1-split (P0) -> z-split (P1)
    gemm_pl<256, 24, 0, true><<<dim3(HDIM / 256, BATCH / 128), 256, 0, stream>>>(
        XS, w1s, eb1, P0, nullptr, nullptr, HDIM);
    gemm_pl<256, 32, 0, false><<<dim3(HDIM / 256, BATCH / 128), 256, 0, stream>>>(
        P0, w2s, eb2, P1, nullptr, nullptr, HDIM);

    // |z|^2 per row
    rownorm<<<BATCH / 4, 256, 0, stream>>>(P1, zn);

    // VQ scores: 4 Gram-corrected argmax GEMMs over the SAME z
    float* idxo = out + OUT_IDX_OFF;
    vq_score<0><<<BATCH / 128, 256, 0, stream>>>(P1, cbw, G6, cn, idxo, ii, ss);
    vq_score<1><<<BATCH / 128, 256, 0, stream>>>(P1, cbw, G6, cn, idxo, ii, ss);
    vq_score<2><<<BATCH / 128, 256, 0, stream>>>(P1, cbw, G6, cn, idxo, ii, ss);
    vq_score<3><<<BATCH / 128, 256, 0, stream>>>(P1, cbw, G6, cn, idxo, ii, ss);

    // quant = sum of chosen codes -> P0 (split), + commit partials
    vq_quant<<<BATCH / 32, 256, 0, stream>>>(ii, ss, zn, cb, P0, cP);

    // decoder: quant (P0) -> hidden (P1) -> recon (out) + loss
    gemm_pl<256, 32, 0, true><<<dim3(HDIM / 256, BATCH / 128), 256, 0, stream>>>(
        P0, w3s, db1, P1, nullptr, nullptr, HDIM);
    gemm_pl<128, 32, 1, false><<<dim3(EDIM / 128, BATCH / 128), 256, 0, stream>>>(
        P1, w4s, db2, out, x, rP, EDIM);

    // losses
    loss_reduce<<<1, 256, 0, stream>>>(cP, BATCH / 32, rP,
                                       (BATCH / 128) * (EDIM / 128),
                                       out + OUT_RL_OFF);
}

// Round 10
// 968.728 us; speedup vs baseline: 1.1924x; 1.0283x over previous
//
#include <hip/hip_runtime.h>
#include <cfloat>
#include <cstddef>
#include <cstdint>

// ---------------------------------------------------------------------------
// SemanticRQVAE forward, round 10.
//   R9 Gram reformulation + (1) bijective XCD swizzle in gemm_pl (A-panel
//   L2 reuse across column-blocks), (2) the 4 score GEMMs fused into one
//   N=1024 GEMM writing raw scores S (f32, into dead P0 region, 2 half-batch
//   passes) + streaming vq_argmax kernel (sequential Gram-corrected argmax,
//   same op order as R9 epilogue -> identical indices).
// Activation format, per row, per k-tile of 16 (64 B):
//   [u=0] h(k0..7) [u=1] h(k8..15) [u=2] l(k0..7) [u=3] l(k8..15)
// d_out layout (floats): recon | indices-as-float | recon_loss | commit_loss
// ---------------------------------------------------------------------------

#define BATCH   65536
#define EDIM    384
#define HDIM    512
#define NCODE   256
#define NQ      4

#define OUT_IDX_OFF 25165824
#define OUT_RL_OFF  25427968
#define WS_P0       0
#define WS_P1       33554432
#define WS_CBW      67108864     // 524288 fl (w-split of all 1024 codes, N=1024)
#define WS_CNORM    67633152
#define WS_COMMITP  67634176
#define WS_RECONP   67636224
#define WS_W1S      67637760
#define WS_W2S      67834368
#define WS_W3S      68096512
#define WS_W4S      68358656     // ends 68555264
#define WS_CBA      68555264     // 524288 fl (act-split of 1024 code rows)
#define WS_G6       69079552     // 393216 fl (6 x 256 x 256)
#define WS_ZN       69472768     // 65536
#define WS_SSTAR    69538304     // 262144 ([q][65536])
#define WS_IDXI     69800448     // 262144 int ([q][65536])

typedef _Float16 half8 __attribute__((ext_vector_type(8)));
typedef float    f32x16 __attribute__((ext_vector_type(16)));

__device__ __forceinline__ void cvt_hl8(const float* vs, half8& h, half8& l)
{
#pragma unroll
    for (int j = 0; j < 8; ++j) {
        _Float16 hv = (_Float16)vs[j];
        h[j] = hv;
        l[j] = (_Float16)(vs[j] - (float)hv);
    }
}

__device__ __forceinline__ void gll16(const unsigned short* g, unsigned short* l)
{
    __builtin_amdgcn_global_load_lds(
        (const __attribute__((address_space(1))) unsigned int*)g,
        (__attribute__((address_space(3))) unsigned int*)l, 16, 0, 0);
}

template <int N> __device__ __forceinline__ void waitvm()
{
    __builtin_amdgcn_sched_barrier(0);
    if constexpr (N == 0)      asm volatile("s_waitcnt vmcnt(0)" ::: "memory");
    else if constexpr (N == 6) asm volatile("s_waitcnt vmcnt(6)" ::: "memory");
    __builtin_amdgcn_sched_barrier(0);
}
__device__ __forceinline__ void barrier_raw()
{
    __builtin_amdgcn_s_barrier();
    __builtin_amdgcn_sched_barrier(0);
}

// ---------------------------------------------------------------------------
// One-shot splits
// ---------------------------------------------------------------------------
__global__ __launch_bounds__(256)
void split_act(const float* __restrict__ src, unsigned short* __restrict__ dst,
               int K)
{
    int u = blockIdx.x * 256 + threadIdx.x;
    int upr = K >> 3;
    int row = u / upr;
    int rem = u % upr;
    int kt = rem >> 1, kh = rem & 1;
    const float* p = src + (size_t)row * K + kt * 16 + kh * 8;
    float vs[8];
#pragma unroll
    for (int j = 0; j < 8; ++j) vs[j] = p[j];
    half8 h, l;
    cvt_hl8(vs, h, l);
    unsigned short* o = dst + (size_t)row * (2 * K) + kt * 32 + kh * 8;
    *reinterpret_cast<half8*>(o)      = h;
    *reinterpret_cast<half8*>(o + 16) = l;
}

__global__ __launch_bounds__(256)
void split_w(const float* __restrict__ W, unsigned short* __restrict__ out,
             int N, int K)
{
    int u = blockIdx.x * 256 + threadIdx.x;
    int col  = u % N;
    int rem  = u / N;
    int khalf = rem & 1;
    int kt    = rem >> 1;
    int kbase = kt * 16 + khalf * 8;
    float vs[8];
#pragma unroll
    for (int j = 0; j < 8; ++j) vs[j] = W[(size_t)(kbase + j) * N + col];
    half8 h, l;
    cvt_hl8(vs, h, l);
    *reinterpret_cast<half8*>(out + ((size_t)(kt * 4 + khalf) * N + col) * 8)     = h;
    *reinterpret_cast<half8*>(out + ((size_t)(kt * 4 + 2 + khalf) * N + col) * 8) = l;
}

// codebook as weight: W[k][n] = cb[n][k], N = 1024, K = 512
__global__ __launch_bounds__(256)
void split_cbw(const float* __restrict__ cb, unsigned short* __restrict__ out)
{
    int u = blockIdx.x * 256 + threadIdx.x;
    int col = u & 1023;
    int rem = u >> 10;
    int kh = rem & 1;
    int kt = rem >> 1;
    const float* p = cb + (size_t)col * HDIM + kt * 16 + kh * 8;
    float vs[8];
#pragma unroll
    for (int j = 0; j < 8; ++j) vs[j] = p[j];
    half8 h, l;
    cvt_hl8(vs, h, l);
    *reinterpret_cast<half8*>(out + ((size_t)(kt * 4 + kh) * 1024 + col) * 8)     = h;
    *reinterpret_cast<half8*>(out + ((size_t)(kt * 4 + 2 + kh) * 1024 + col) * 8) = l;
}

__global__ __launch_bounds__(64)
void cnorm_kernel(const float* __restrict__ cb, float* __restrict__ cnorm)
{
    const int code = blockIdx.x;
    const int lane = threadIdx.x;
    const float* r = cb + (size_t)code * HDIM;
    float s = 0.f;
    for (int k = lane; k < HDIM; k += 64) s = fmaf(r[k], r[k], s);
#pragma unroll
    for (int off = 32; off > 0; off >>= 1) s += __shfl_down(s, off);
    if (lane == 0) cnorm[code] = s;
}

// |z|^2 per row from split storage
__global__ __launch_bounds__(256)
void rownorm(const unsigned short* __restrict__ zs, float* __restrict__ zn)
{
    const int tid = threadIdx.x, wid = tid >> 6, lane = tid & 63;
    const int row = blockIdx.x * 4 + wid;
    const unsigned short* p = zs + (size_t)row * 1024
                                 + (lane >> 1) * 32 + (lane & 1) * 8;
    half8 h = *reinterpret_cast<const half8*>(p);
    half8 l = *reinterpret_cast<const half8*>(p + 16);
    float s = 0.f;
#pragma unroll
    for (int e = 0; e < 8; ++e) {
        float v = (float)h[e] + (float)l[e];
        s = fmaf(v, v, s);
    }
#pragma unroll
    for (int off = 32; off > 0; off >>= 1) s += __shfl_down(s, off);
    if (lane == 0) zn[row] = s;
}

// ---------------------------------------------------------------------------
// Pipelined MFMA GEMM (R6-proven core) + bijective XCD swizzle.
// OMODE 0: split-act out; 1: f32 + recon loss; 2: raw f32 out (ldc param).
// ---------------------------------------------------------------------------
template <int BN, int NKT, int OMODE, bool RELU>
__global__ __launch_bounds__(256, 2)
void gemm_pl(const unsigned short* __restrict__ Ain,
             const unsigned short* __restrict__ Wsp,
             const float* __restrict__ bias, void* __restrict__ Cout,
             const float* __restrict__ X, float* __restrict__ lossP,
             int N, int ldc)
{
    constexpr int WN  = BN / 128;
    constexpr int WM  = 4 / WN;
    constexpr int MR  = 128 / WM;
    constexpr int FM  = MR / 32;
    constexpr int K   = NKT * 16;
    constexpr int BOFF = 4096;
    constexpr int BUFU = 4096 + 4 * BN * 8;
    constexpr int NIB = BN / 64;

    __shared__ __align__(16) unsigned short lds[3][BUFU];

    const int tid  = threadIdx.x;
    const int wid  = tid >> 6;
    const int lane = tid & 63;
    const int l31  = lane & 31;
    const int lh   = lane >> 5;
    const int wm   = wid / WN;
    const int wn   = wid % WN;

    // bijective XCD-chunked swizzle (identity when nwg not divisible by 8)
    int bidx = blockIdx.y * gridDim.x + blockIdx.x;
    const int nwg = gridDim.x * gridDim.y;
    if ((nwg & 7) == 0) {
        const int cpx = nwg >> 3;
        bidx = (bidx & 7) * cpx + (bidx >> 3);
    }
    const int bx = bidx % gridDim.x;
    const int by = bidx / gridDim.x;
    const int row0 = by * 128;
    const int n0   = bx * BN;

    f32x16 acc[FM][4];
#pragma unroll
    for (int m = 0; m < FM; ++m)
#pragma unroll
        for (int n = 0; n < 4; ++n) acc[m][n] = (f32x16)(0.0f);

    auto stageB = [&](int buf, int kt) {
        const unsigned short* img = Wsp + (size_t)kt * 4 * N * 8;
        unsigned short* dstb = &lds[buf][BOFF];
#pragma unroll
        for (int t = 0; t < NIB; ++t) {
            int e = (wid * NIB + t) * 64 + lane;
            int u = (BN == 256) ? (e >> 8) : (e >> 7);
            int c = e & (BN - 1);
            gll16(img + ((size_t)u * N + n0 + c) * 8, dstb + (size_t)e * 8);
        }
    };
    auto stageA = [&](int buf, int kt) {
#pragma unroll
        for (int t = 0; t < 2; ++t) {
            int i = wid * 2 + t;
            int u = i >> 1, rh = i & 1;
            int row = rh * 64 + lane;
            gll16(Ain + (size_t)(row0 + row) * (2 * K) + kt * 32 + u * 8,
                  &lds[buf][(size_t)i * 512 + (size_t)lane * 8]);
        }
    };
    auto compute = [&](int buf) {
        const unsigned short* Ab = &lds[buf][0];
        const unsigned short* Bb = &lds[buf][BOFF];
        half8 Ah[FM], Al[FM];
#pragma unroll
        for (int fm = 0; fm < FM; ++fm) {
            int row = wm * MR + fm * 32 + l31;
            Ah[fm] = *reinterpret_cast<const half8*>(Ab + (size_t)lh * 1024 + (size_t)row * 8);
            Al[fm] = *reinterpret_cast<const half8*>(Ab + (size_t)(2 + lh) * 1024 + (size_t)row * 8);
        }
#pragma unroll
        for (int nt = 0; nt < 4; ++nt) {
            int col = wn * 128 + nt * 32 + l31;
            half8 Bh = *reinterpret_cast<const half8*>(Bb + (size_t)lh * BN * 8 + (size_t)col * 8);
            half8 Bl = *reinterpret_cast<const half8*>(Bb + (size_t)(2 + lh) * BN * 8 + (size_t)col * 8);
#pragma unroll
            for (int fm = 0; fm < FM; ++fm) {
                acc[fm][nt] = __builtin_amdgcn_mfma_f32_32x32x16_f16(Ah[fm], Bh, acc[fm][nt], 0, 0, 0);
                acc[fm][nt] = __builtin_amdgcn_mfma_f32_32x32x16_f16(Ah[fm], Bl, acc[fm][nt], 0, 0, 0);
                acc[fm][nt] = __builtin_amdgcn_mfma_f32_32x32x16_f16(Al[fm], Bh, acc[fm][nt], 0, 0, 0);
            }
        }
    };

    stageA(0, 0); stageB(0, 0);
    stageA(1, 1); stageB(1, 1);
    waitvm<6>();
    barrier_raw();
    for (int kt = 0; kt < NKT; ++kt) {
        const int cur = kt % 3;
        if (kt + 2 < NKT) { const int nb = (kt + 2) % 3; stageA(nb, kt + 2); stageB(nb, kt + 2); }
        compute(cur);
        if (kt < NKT - 2) waitvm<6>(); else waitvm<0>();
        barrier_raw();
    }

    if constexpr (OMODE == 0) {
        unsigned short* o = (unsigned short*)Cout;
        const size_t rs = (size_t)N * 2;
#pragma unroll
        for (int fm = 0; fm < FM; ++fm) {
#pragma unroll
            for (int nt = 0; nt < 4; ++nt) {
                const int col = n0 + wn * 128 + nt * 32 + l31;
                const float b = bias[col];
                const size_t cbo = (size_t)(col >> 4) * 32 + (size_t)((col >> 3) & 1) * 8 + (col & 7);
#pragma unroll
                for (int rg = 0; rg < 16; ++rg) {
                    const int row = row0 + wm * MR + fm * 32 + (rg & 3) + 8 * (rg >> 2) + 4 * lh;
                    float v = acc[fm][nt][rg] + b;
                    if (RELU) v = v > 0.f ? v : 0.f;
                    _Float16 hv = (_Float16)v;
                    _Float16 lv = (_Float16)(v - (float)hv);
                    union { _Float16 f; unsigned short u; } ch, cl;
                    ch.f = hv; cl.f = lv;
                    o[(size_t)row * rs + cbo]      = ch.u;
                    o[(size_t)row * rs + cbo + 16] = cl.u;
                }
            }
        }
    } else if constexpr (OMODE == 1) {
        float* C = (float*)Cout;
        float lacc = 0.f;
#pragma unroll
        for (int fm = 0; fm < FM; ++fm) {
#pragma unroll
            for (int nt = 0; nt < 4; ++nt) {
                const int col = n0 + wn * 128 + nt * 32 + l31;
                const float b = bias[col];
#pragma unroll
                for (int rg = 0; rg < 16; ++rg) {
                    const int row = row0 + wm * MR + fm * 32 + (rg & 3) + 8 * (rg >> 2) + 4 * lh;
                    float v = acc[fm][nt][rg] + b;
                    if (RELU) v = v > 0.f ? v : 0.f;
                    C[(size_t)row * N + col] = v;
                    float d = v - X[(size_t)row * N + col];
                    lacc = fmaf(d, d, lacc);
                }
            }
        }
        __shared__ float red[256];
        red[tid] = lacc;
        __syncthreads();
        for (int s = 128; s > 0; s >>= 1) {
            if (tid < s) red[tid] += red[tid + s];
            __syncthreads();
        }
        if (tid == 0) lossP[by * gridDim.x + bx] = red[0];
    } else {
        // OMODE 2: raw f32, row stride = ldc, no bias (Gram blocks, scores)
        float* C = (float*)Cout;
#pragma unroll
        for (int fm = 0; fm < FM; ++fm) {
#pragma unroll
            for (int nt = 0; nt < 4; ++nt) {
                const int col = n0 + wn * 128 + nt * 32 + l31;
#pragma unroll
                for (int rg = 0; rg < 16; ++rg) {
                    const int row = row0 + wm * MR + fm * 32 + (rg & 3) + 8 * (rg >> 2) + 4 * lh;
                    C[(size_t)row * ldc + col] = acc[fm][nt][rg];
                }
            }
        }
    }
}

// ---------------------------------------------------------------------------
// Sequential Gram-corrected argmax over materialized scores S [rows][1024].
// One wave per row (4 rows / 256-thread block). Op order identical to R9's
// epilogue: a = S; a -= g(0,q); a -= g(1,q); a -= g(2,3); s = 2a - cnorm.
// First-max tie-break (min code among max).
// ---------------------------------------------------------------------------
__global__ __launch_bounds__(256)
void vq_argmax(const float* __restrict__ S,
               const float* __restrict__ G6,
               const float* __restrict__ cnorm,
               float* __restrict__ idx_out,
               int* __restrict__ idxi,
               float* __restrict__ sstar,
               int rowbase)
{
    const int tid = threadIdx.x, wid = tid >> 6, lane = tid & 63;
    const int lrow = blockIdx.x * 4 + wid;
    const int grow = rowbase + lrow;
    const float* srow = S + (size_t)lrow * 1024;
    const int c0 = lane * 4;

    int iprev0 = 0, iprev1 = 0, iprev2 = 0;

#pragma unroll
    for (int q = 0; q < NQ; ++q) {
        float4 sv = *reinterpret_cast<const float4*>(srow + q * 256 + c0);
        float a[4] = {sv.x, sv.y, sv.z, sv.w};
        if (q >= 1) {        // pair (0,q) = q-1
            const float* g = G6 + ((size_t)(q - 1) * 256 + iprev0) * 256 + c0;
            float4 gv = *reinterpret_cast<const float4*>(g);
            a[0] -= gv.x; a[1] -= gv.y; a[2] -= gv.z; a[3] -= gv.w;
        }
        if (q >= 2) {        // pair (1,q) = q+1  (q=2->3, q=3->4)
            const float* g = G6 + ((size_t)(q + 1) * 256 + iprev1) * 256 + c0;
            float4 gv = *reinterpret_cast<const float4*>(g);
            a[0] -= gv.x; a[1] -= gv.y; a[2] -= gv.z; a[3] -= gv.w;
        }
        if (q >= 3) {        // pair (2,3) = 5
            const float* g = G6 + ((size_t)5 * 256 + iprev2) * 256 + c0;
            float4 gv = *reinterpret_cast<const float4*>(g);
            a[0] -= gv.x; a[1] -= gv.y; a[2] -= gv.z; a[3] -= gv.w;
        }
        float4 cnv = *reinterpret_cast<const float4*>(cnorm + q * 256 + c0);
        float cna[4] = {cnv.x, cnv.y, cnv.z, cnv.w};

        float bv = -FLT_MAX;
        int   bi = 0;
#pragma unroll
        for (int j = 0; j < 4; ++j) {
            float s = 2.f * a[j] - cna[j];
            const int code = c0 + j;
            if (s > bv || (s == bv && code < bi)) { bv = s; bi = code; }
        }
#pragma unroll
        for (int m = 1; m < 64; m <<= 1) {
            float ov = __shfl_xor(bv, m, 64);
            int   oi = __shfl_xor(bi, m, 64);
            if (ov > bv || (ov == bv && oi < bi)) { bv = ov; bi = oi; }
        }
        // bv/bi uniform across wave now
        if (q == 0) iprev0 = bi;
        else if (q == 1) iprev1 = bi;
        else if (q == 2) iprev2 = bi;
        if (lane == 0) {
            idxi[q * 65536 + grow]  = bi;
            sstar[q * 65536 + grow] = bv;
            idx_out[(size_t)grow * NQ + q] = (float)bi;
        }
    }
}

// ---------------------------------------------------------------------------
// quant = sum of chosen codes (split out) + commit partials.
// ---------------------------------------------------------------------------
__global__ __launch_bounds__(256)
void vq_quant(const int* __restrict__ idxi, const float* __restrict__ sstar,
              const float* __restrict__ zn, const float* __restrict__ cb,
              unsigned short* __restrict__ qout, float* __restrict__ commitP)
{
    __shared__ float red[256];
    const int tid = threadIdx.x, wid = tid >> 6, lane = tid & 63;
    float ca = 0.f;

#pragma unroll
    for (int t = 0; t < 8; ++t) {
        const int row = blockIdx.x * 32 + wid * 8 + t;
        const int i0 = idxi[row],          i1 = idxi[65536 + row];
        const int i2 = idxi[131072 + row], i3 = idxi[196608 + row];
        const int koff = lane * 8;
        const float* c0 = cb + ((size_t)(0 * NCODE + i0)) * HDIM + koff;
        const float* c1 = cb + ((size_t)(1 * NCODE + i1)) * HDIM + koff;
        const float* c2 = cb + ((size_t)(2 * NCODE + i2)) * HDIM + koff;
        const float* c3 = cb + ((size_t)(3 * NCODE + i3)) * HDIM + koff;
        float q[8];
#pragma unroll
        for (int half = 0; half < 2; ++half) {
            float4 v0 = *reinterpret_cast<const float4*>(c0 + half * 4);
            float4 v1 = *reinterpret_cast<const float4*>(c1 + half * 4);
            float4 v2 = *reinterpret_cast<const float4*>(c2 + half * 4);
            float4 v3 = *reinterpret_cast<const float4*>(c3 + half * 4);
            q[half * 4 + 0] = ((v0.x + v1.x) + v2.x) + v3.x;
            q[half * 4 + 1] = ((v0.y + v1.y) + v2.y) + v3.y;
            q[half * 4 + 2] = ((v0.z + v1.z) + v2.z) + v3.z;
            q[half * 4 + 3] = ((v0.w + v1.w) + v2.w) + v3.w;
        }
        half8 oh, ol;
        cvt_hl8(q, oh, ol);
        unsigned short* op = qout + (size_t)row * 1024
                                  + (lane >> 1) * 32 + (lane & 1) * 8;
        *reinterpret_cast<half8*>(op)      = oh;
        *reinterpret_cast<half8*>(op + 16) = ol;

        if (lane == 0) {
            float rn = zn[row];
            rn -= sstar[row];           float cm = rn;
            rn -= sstar[65536 + row];   cm += rn;
            rn -= sstar[131072 + row];  cm += rn;
            rn -= sstar[196608 + row];  cm += rn;
            ca += cm;
        }
    }

    red[tid] = ca;
    __syncthreads();
    for (int s = 128; s > 0; s >>= 1) {
        if (tid < s) red[tid] += red[tid + s];
        __syncthreads();
    }
    if (tid == 0) commitP[blockIdx.x] = red[0];
}

// ---------------------------------------------------------------------------
__global__ __launch_bounds__(256)
void loss_reduce(const float* __restrict__ cP, int nc,
                 const float* __restrict__ rP, int nr,
                 float* __restrict__ out2)
{
    __shared__ float red[256];
    const int tid = threadIdx.x;

    float s = 0.f;
    for (int i = tid; i < nc; i += 256) s += cP[i];
    red[tid] = s;
    __syncthreads();
    for (int st = 128; st > 0; st >>= 1) {
        if (tid < st) red[tid] += red[tid + st];
        __syncthreads();
    }
    float ctot = red[0];
    __syncthreads();

    s = 0.f;
    for (int i = tid; i < nr; i += 256) s += rP[i];
    red[tid] = s;
    __syncthreads();
    for (int st = 128; st > 0; st >>= 1) {
        if (tid < st) red[tid] += red[tid + st];
        __syncthreads();
    }
    if (tid == 0) {
        out2[0] = red[0] / ((float)BATCH * (float)EDIM);
        out2[1] = 0.25f * ctot / ((float)BATCH * (float)HDIM);
    }
}

// ---------------------------------------------------------------------------
extern "C" void kernel_launch(void* const* d_in, const int* in_sizes, int n_in,
                              void* d_out, int out_size, void* d_ws, size_t ws_size,
                              hipStream_t stream)
{
    const float* x   = (const float*)d_in[0];
    const float* ew1 = (const float*)d_in[1];
    const float* eb1 = (const float*)d_in[2];
    const float* ew2 = (const float*)d_in[3];
    const float* eb2 = (const float*)d_in[4];
    const float* cb  = (const float*)d_in[5];
    const float* dw1 = (const float*)d_in[6];
    const float* db1 = (const float*)d_in[7];
    const float* dw2 = (const float*)d_in[8];
    const float* db2 = (const float*)d_in[9];

    float* out = (float*)d_out;
    float* ws  = (float*)d_ws;
    unsigned short* P0  = (unsigned short*)(ws + WS_P0);
    unsigned short* P1  = (unsigned short*)(ws + WS_P1);
    unsigned short* XS  = P1;                    // x-split aliased into P1
    float* Sbuf = ws + WS_P0;                    // scores alias P0 (h1 dead)
    unsigned short* cbw = (unsigned short*)(ws + WS_CBW);
    unsigned short* cba = (unsigned short*)(ws + WS_CBA);
    float* G6 = ws + WS_G6;
    float* zn = ws + WS_ZN;
    float* ss = ws + WS_SSTAR;
    int*   ii = (int*)(ws + WS_IDXI);
    float* cn = ws + WS_CNORM;
    float* cP = ws + WS_COMMITP;
    float* rP = ws + WS_RECONP;
    unsigned short* w1s = (unsigned short*)(ws + WS_W1S);
    unsigned short* w2s = (unsigned short*)(ws + WS_W2S);
    unsigned short* w3s = (unsigned short*)(ws + WS_W3S);
    unsigned short* w4s = (unsigned short*)(ws + WS_W4S);

    // prep: norms + splits
    cnorm_kernel<<<NQ * NCODE, 64, 0, stream>>>(cb, cn);
    split_act<<<BATCH * 48 / 256, 256, 0, stream>>>(x, XS, EDIM);
    split_act<<<1024 * 64 / 256, 256, 0, stream>>>(cb, cba, HDIM);
    split_cbw<<<256, 256, 0, stream>>>(cb, cbw);
    split_w<<<(EDIM / 16) * 2 * HDIM / 256, 256, 0, stream>>>(ew1, w1s, HDIM, EDIM);
    split_w<<<(HDIM / 16) * 2 * HDIM / 256, 256, 0, stream>>>(ew2, w2s, HDIM, HDIM);
    split_w<<<(HDIM / 16) * 2 * HDIM / 256, 256, 0, stream>>>(dw1, w3s, HDIM, HDIM);
    split_w<<<(HDIM / 16) * 2 * EDIM / 256, 256, 0, stream>>>(dw2, w4s, EDIM, HDIM);

    // Gram blocks G6[pair] = C_p . C_q^T
    {
        const int pairs[6][2] = {{0,1},{0,2},{0,3},{1,2},{1,3},{2,3}};
        for (int pi = 0; pi < 6; ++pi) {
            const int p = pairs[pi][0], q = pairs[pi][1];
            gemm_pl<256, 32, 2, false><<<dim3(1, 2), 256, 0, stream>>>(
                cba + (size_t)p * 256 * 1024, cbw + (size_t)q * 256 * 8,
                nullptr, G6 + (size_t)pi * 65536, nullptr, nullptr, 1024, 256);
        }
    }

    // encoder: x-split (P1) -> h1-split (P0) -> z-split (P1)
    gemm_pl<256, 24, 0, true><<<dim3(HDIM / 256, BATCH / 128), 256, 0, stream>>>(
        XS, w1s, eb1, P0, nullptr, nullptr, HDIM, HDIM);
    gemm_pl<256, 32, 0, false><<<dim3(HDIM / 256, BATCH / 128), 256, 0, stream>>>(
        P0, w2s, eb2, P1, nullptr, nullptr, HDIM, HDIM);

    // |z|^2 per row
    rownorm<<<BATCH / 4, 256, 0, stream>>>(P1, zn);

    // fused score GEMM (all 4 codebooks, N=1024) + streaming argmax,
    // two half-batch passes through the P0 score buffer (32768 x 1024 f32)
    float* idxo = out + OUT_IDX_OFF;
    for (int half = 0; half < 2; ++half) {
        const int rowbase = half * 32768;
        gemm_pl<256, 32, 2, false><<<dim3(4, 256), 256, 0, stream>>>(
            P1 + (size_t)rowbase * 1024, cbw, nullptr, Sbuf,
            nullptr, nullptr, 1024, 1024);
        vq_argmax<<<8192, 256, 0, stream>>>(Sbuf, G6, cn, idxo, ii, ss, rowbase);
    }

    // quant = sum of chosen codes -> P0 (split), + commit partials
    vq_quant<<<BATCH / 32, 256, 0, stream>>>(ii, ss, zn, cb, P0, cP);

    // decoder: quant (P0) -> hidden (P1) -> recon (out) + loss
    gemm_pl<256, 32, 0, true><<<dim3(HDIM / 256, BATCH / 128), 256, 0, stream>>>(
        P0, w3s, db1, P1, nullptr, nullptr, HDIM, HDIM);
    gemm_pl<128, 32, 1, false><<<dim3(EDIM / 128, BATCH / 128), 256, 0, stream>>>(
        P1, w4s, db2, out, x, rP, EDIM, EDIM);

    // losses
    loss_reduce<<<1, 256, 0, stream>>>(cP, BATCH / 32, rP,
                                       (BATCH / 128) * (EDIM / 128),
                                       out + OUT_RL_OFF);
}

// Round 11
// 891.827 us; speedup vs baseline: 1.2952x; 1.0862x over previous
//
#include <hip/hip_runtime.h>
#include <cfloat>
#include <cstddef>
#include <cstdint>

// ---------------------------------------------------------------------------
// SemanticRQVAE forward, round 11.
//   R10 Gram formulation, retiled GEMM: 8 waves / 512 threads, BM=256
//   (more MFMA per barrier-pair; counted-vmcnt 3-ring preserved), fused
//   single-dispatch Gram (OMODE 3) and fused weight-split kernel.
// Activation format, per row, per k-tile of 16 (64 B):
//   [u=0] h(k0..7) [u=1] h(k8..15) [u=2] l(k0..7) [u=3] l(k8..15)
// d_out layout (floats): recon | indices-as-float | recon_loss | commit_loss
// ---------------------------------------------------------------------------

#define BATCH   65536
#define EDIM    384
#define HDIM    512
#define NCODE   256
#define NQ      4

#define OUT_IDX_OFF 25165824
#define OUT_RL_OFF  25427968
#define WS_P0       0
#define WS_P1       33554432
#define WS_CBW      67108864
#define WS_CNORM    67633152
#define WS_COMMITP  67634176
#define WS_RECONP   67636224
#define WS_W1S      67637760
#define WS_W2S      67834368
#define WS_W3S      68096512
#define WS_W4S      68358656
#define WS_CBA      68555264
#define WS_G6       69079552
#define WS_ZN       69472768
#define WS_SSTAR    69538304
#define WS_IDXI     69800448

typedef _Float16 half8 __attribute__((ext_vector_type(8)));
typedef float    f32x16 __attribute__((ext_vector_type(16)));

__device__ __forceinline__ void cvt_hl8(const float* vs, half8& h, half8& l)
{
#pragma unroll
    for (int j = 0; j < 8; ++j) {
        _Float16 hv = (_Float16)vs[j];
        h[j] = hv;
        l[j] = (_Float16)(vs[j] - (float)hv);
    }
}

__device__ __forceinline__ void gll16(const unsigned short* g, unsigned short* l)
{
    __builtin_amdgcn_global_load_lds(
        (const __attribute__((address_space(1))) unsigned int*)g,
        (__attribute__((address_space(3))) unsigned int*)l, 16, 0, 0);
}

template <int N> __device__ __forceinline__ void waitvm()
{
    __builtin_amdgcn_sched_barrier(0);
    if constexpr (N == 0)      asm volatile("s_waitcnt vmcnt(0)" ::: "memory");
    else if constexpr (N == 3) asm volatile("s_waitcnt vmcnt(3)" ::: "memory");
    else if constexpr (N == 4) asm volatile("s_waitcnt vmcnt(4)" ::: "memory");
    else if constexpr (N == 6) asm volatile("s_waitcnt vmcnt(6)" ::: "memory");
    __builtin_amdgcn_sched_barrier(0);
}
__device__ __forceinline__ void barrier_raw()
{
    __builtin_amdgcn_s_barrier();
    __builtin_amdgcn_sched_barrier(0);
}

// ---------------------------------------------------------------------------
// splits
// ---------------------------------------------------------------------------
__global__ __launch_bounds__(256)
void split_act(const float* __restrict__ src, unsigned short* __restrict__ dst,
               int K)
{
    int u = blockIdx.x * 256 + threadIdx.x;
    int upr = K >> 3;
    int row = u / upr;
    int rem = u % upr;
    int kt = rem >> 1, kh = rem & 1;
    const float* p = src + (size_t)row * K + kt * 16 + kh * 8;
    float vs[8];
#pragma unroll
    for (int j = 0; j < 8; ++j) vs[j] = p[j];
    half8 h, l;
    cvt_hl8(vs, h, l);
    unsigned short* o = dst + (size_t)row * (2 * K) + kt * 32 + kh * 8;
    *reinterpret_cast<half8*>(o)      = h;
    *reinterpret_cast<half8*>(o + 16) = l;
}

__device__ __forceinline__ void body_split_w(const float* __restrict__ W,
                                             unsigned short* __restrict__ out,
                                             int N, int u)
{
    int col  = u % N;
    int rem  = u / N;
    int kh   = rem & 1;
    int kt   = rem >> 1;
    int kbase = kt * 16 + kh * 8;
    float vs[8];
#pragma unroll
    for (int j = 0; j < 8; ++j) vs[j] = W[(size_t)(kbase + j) * N + col];
    half8 h, l;
    cvt_hl8(vs, h, l);
    *reinterpret_cast<half8*>(out + ((size_t)(kt * 4 + kh) * N + col) * 8)     = h;
    *reinterpret_cast<half8*>(out + ((size_t)(kt * 4 + 2 + kh) * N + col) * 8) = l;
}

__device__ __forceinline__ void body_split_cbw(const float* __restrict__ cb,
                                               unsigned short* __restrict__ out,
                                               int u)
{
    int col = u & 1023;
    int rem = u >> 10;
    int kh = rem & 1;
    int kt = rem >> 1;
    const float* p = cb + (size_t)col * HDIM + kt * 16 + kh * 8;
    float vs[8];
#pragma unroll
    for (int j = 0; j < 8; ++j) vs[j] = p[j];
    half8 h, l;
    cvt_hl8(vs, h, l);
    *reinterpret_cast<half8*>(out + ((size_t)(kt * 4 + kh) * 1024 + col) * 8)     = h;
    *reinterpret_cast<half8*>(out + ((size_t)(kt * 4 + 2 + kh) * 1024 + col) * 8) = l;
}

__device__ __forceinline__ void body_split_cba(const float* __restrict__ cb,
                                               unsigned short* __restrict__ out,
                                               int u)
{
    int row = u >> 6;          // 0..1023
    int rem = u & 63;
    int kt = rem >> 1, kh = rem & 1;
    const float* p = cb + (size_t)row * HDIM + kt * 16 + kh * 8;
    float vs[8];
#pragma unroll
    for (int j = 0; j < 8; ++j) vs[j] = p[j];
    half8 h, l;
    cvt_hl8(vs, h, l);
    unsigned short* o = out + (size_t)row * 1024 + kt * 32 + kh * 8;
    *reinterpret_cast<half8*>(o)      = h;
    *reinterpret_cast<half8*>(o + 16) = l;
}

// fused: w1 (96 blk) | w2 (128) | w3 (128) | w4 (96) | cbw (256) | cba (256)
__global__ __launch_bounds__(256)
void split_wall(const float* __restrict__ ew1, const float* __restrict__ ew2,
                const float* __restrict__ dw1, const float* __restrict__ dw2,
                const float* __restrict__ cb,
                unsigned short* __restrict__ w1s, unsigned short* __restrict__ w2s,
                unsigned short* __restrict__ w3s, unsigned short* __restrict__ w4s,
                unsigned short* __restrict__ cbw, unsigned short* __restrict__ cba)
{
    const int b = blockIdx.x, tid = threadIdx.x;
    if (b < 96)        body_split_w(ew1, w1s, HDIM, b * 256 + tid);
    else if (b < 224)  body_split_w(ew2, w2s, HDIM, (b - 96) * 256 + tid);
    else if (b < 352)  body_split_w(dw1, w3s, HDIM, (b - 224) * 256 + tid);
    else if (b < 448)  body_split_w(dw2, w4s, EDIM, (b - 352) * 256 + tid);
    else if (b < 704)  body_split_cbw(cb, cbw, (b - 448) * 256 + tid);
    else               body_split_cba(cb, cba, (b - 704) * 256 + tid);
}

__global__ __launch_bounds__(64)
void cnorm_kernel(const float* __restrict__ cb, float* __restrict__ cnorm)
{
    const int code = blockIdx.x;
    const int lane = threadIdx.x;
    const float* r = cb + (size_t)code * HDIM;
    float s = 0.f;
    for (int k = lane; k < HDIM; k += 64) s = fmaf(r[k], r[k], s);
#pragma unroll
    for (int off = 32; off > 0; off >>= 1) s += __shfl_down(s, off);
    if (lane == 0) cnorm[code] = s;
}

__global__ __launch_bounds__(256)
void rownorm(const unsigned short* __restrict__ zs, float* __restrict__ zn)
{
    const int tid = threadIdx.x, wid = tid >> 6, lane = tid & 63;
    const int row = blockIdx.x * 4 + wid;
    const unsigned short* p = zs + (size_t)row * 1024
                                 + (lane >> 1) * 32 + (lane & 1) * 8;
    half8 h = *reinterpret_cast<const half8*>(p);
    half8 l = *reinterpret_cast<const half8*>(p + 16);
    float s = 0.f;
#pragma unroll
    for (int e = 0; e < 8; ++e) {
        float v = (float)h[e] + (float)l[e];
        s = fmaf(v, v, s);
    }
#pragma unroll
    for (int off = 32; off > 0; off >>= 1) s += __shfl_down(s, off);
    if (lane == 0) zn[row] = s;
}

// ---------------------------------------------------------------------------
// Pipelined MFMA GEMM, 8 waves / BM=256. Counted-vmcnt 3-ring (R6-proven).
// OMODE 0: split-act out; 1: f32 + recon loss; 2: raw f32 (ldc);
// OMODE 3: Gram mode — grid (6,1), pair = blockIdx.x, writes G6[pair].
// ---------------------------------------------------------------------------
template <int BN, int NKT, int OMODE, bool RELU>
__global__ __launch_bounds__(512, 2)
void gemm_pl(const unsigned short* __restrict__ Ain,
             const unsigned short* __restrict__ Wsp,
             const float* __restrict__ bias, void* __restrict__ Cout,
             const float* __restrict__ X, float* __restrict__ lossP,
             int N, int ldc)
{
    constexpr int WN  = BN / 64;              // waves along N
    constexpr int WM  = 8 / WN;               // waves along M
    constexpr int MR  = 256 / WM;             // rows per wave
    constexpr int FM  = MR / 32;              // row frags per wave
    constexpr int K   = NKT * 16;
    constexpr int BOFF = 8192;                // A = 8192 u16 per buffer
    constexpr int BUFU = 8192 + 32 * BN;      // + B 32*BN u16
    constexpr int GPI  = 2 + ((BN == 256) ? 2 : 1);

    __shared__ __align__(16) unsigned short lds[3][BUFU];

    const int tid  = threadIdx.x;
    const int wid  = tid >> 6;                // 0..7
    const int lane = tid & 63;
    const int l31  = lane & 31;
    const int lh   = lane >> 5;
    const int wm   = wid / WN;
    const int wn   = wid % WN;

    int row0, n0, bx = 0, by = 0, pair = 0;
    const unsigned short* Abase = Ain;
    if constexpr (OMODE == 3) {
        const int ptab[6] = {0, 0, 0, 1, 1, 2};
        const int qtab[6] = {1, 2, 3, 2, 3, 3};
        pair = blockIdx.x;
        Abase = Ain + (size_t)ptab[pair] * 256 * 1024;
        row0 = 0;
        n0   = qtab[pair] * 256;
    } else {
        int bidx = blockIdx.y * gridDim.x + blockIdx.x;
        const int nwg = gridDim.x * gridDim.y;
        if ((nwg & 7) == 0) {
            const int cpx = nwg >> 3;
            bidx = (bidx & 7) * cpx + (bidx >> 3);
        }
        bx = bidx % gridDim.x;
        by = bidx / gridDim.x;
        row0 = by * 256;
        n0   = bx * BN;
    }

    f32x16 acc[FM][2];
#pragma unroll
    for (int m = 0; m < FM; ++m)
#pragma unroll
        for (int n = 0; n < 2; ++n) acc[m][n] = (f32x16)(0.0f);

    auto stageA = [&](int buf, int kt) {
#pragma unroll
        for (int t = 0; t < 2; ++t) {
            const int i = t * 8 + wid;        // 0..15
            const int u = i >> 2;
            const int row = (i & 3) * 64 + lane;
            gll16(Abase + (size_t)(row0 + row) * (2 * K) + kt * 32 + u * 8,
                  &lds[buf][(size_t)i * 512 + (size_t)lane * 8]);
        }
    };
    auto stageB = [&](int buf, int kt) {
        const unsigned short* img = Wsp + (size_t)kt * 4 * N * 8;
        unsigned short* dstb = &lds[buf][BOFF];
        if constexpr (BN == 256) {
#pragma unroll
            for (int t = 0; t < 2; ++t) {
                const int i = t * 8 + wid;
                const int u = i >> 2;
                const int col = (i & 3) * 64 + lane;
                gll16(img + ((size_t)u * N + n0 + col) * 8,
                      dstb + (size_t)i * 512 + (size_t)lane * 8);
            }
        } else {
            const int u = wid >> 1;
            const int col = (wid & 1) * 64 + lane;
            gll16(img + ((size_t)u * N + n0 + col) * 8,
                  dstb + (size_t)wid * 512 + (size_t)lane * 8);
        }
    };
    auto compute = [&](int buf) {
        const unsigned short* Ab = &lds[buf][0];
        const unsigned short* Bb = &lds[buf][BOFF];
        half8 Ah[FM], Al[FM];
#pragma unroll
        for (int fm = 0; fm < FM; ++fm) {
            const int row = wm * MR + fm * 32 + l31;
            Ah[fm] = *reinterpret_cast<const half8*>(Ab + ((size_t)lh * 256 + row) * 8);
            Al[fm] = *reinterpret_cast<const half8*>(Ab + ((size_t)(2 + lh) * 256 + row) * 8);
        }
#pragma unroll
        for (int nt = 0; nt < 2; ++nt) {
            const int col = wn * 64 + nt * 32 + l31;
            half8 Bh = *reinterpret_cast<const half8*>(Bb + ((size_t)lh * BN + col) * 8);
            half8 Bl = *reinterpret_cast<const half8*>(Bb + ((size_t)(2 + lh) * BN + col) * 8);
#pragma unroll
            for (int fm = 0; fm < FM; ++fm) {
                acc[fm][nt] = __builtin_amdgcn_mfma_f32_32x32x16_f16(Ah[fm], Bh, acc[fm][nt], 0, 0, 0);
                acc[fm][nt] = __builtin_amdgcn_mfma_f32_32x32x16_f16(Ah[fm], Bl, acc[fm][nt], 0, 0, 0);
                acc[fm][nt] = __builtin_amdgcn_mfma_f32_32x32x16_f16(Al[fm], Bh, acc[fm][nt], 0, 0, 0);
            }
        }
    };

    stageA(0, 0); stageB(0, 0);
    stageA(1, 1); stageB(1, 1);
    waitvm<GPI>();
    barrier_raw();
    for (int kt = 0; kt < NKT; ++kt) {
        const int cur = kt % 3;
        if (kt + 2 < NKT) { const int nb = (kt + 2) % 3; stageA(nb, kt + 2); stageB(nb, kt + 2); }
        compute(cur);
        if (kt < NKT - 2) waitvm<GPI>(); else waitvm<0>();
        barrier_raw();
    }

    if constexpr (OMODE == 0) {
        unsigned short* o = (unsigned short*)Cout;
        const size_t rs = (size_t)N * 2;
#pragma unroll
        for (int fm = 0; fm < FM; ++fm) {
#pragma unroll
            for (int nt = 0; nt < 2; ++nt) {
                const int col = n0 + wn * 64 + nt * 32 + l31;
                const float b = bias[col];
                const size_t cbo = (size_t)(col >> 4) * 32 + (size_t)((col >> 3) & 1) * 8 + (col & 7);
#pragma unroll
                for (int rg = 0; rg < 16; ++rg) {
                    const int row = row0 + wm * MR + fm * 32 + (rg & 3) + 8 * (rg >> 2) + 4 * lh;
                    float v = acc[fm][nt][rg] + b;
                    if (RELU) v = v > 0.f ? v : 0.f;
                    _Float16 hv = (_Float16)v;
                    _Float16 lv = (_Float16)(v - (float)hv);
                    union { _Float16 f; unsigned short u; } ch, cl;
                    ch.f = hv; cl.f = lv;
                    o[(size_t)row * rs + cbo]      = ch.u;
                    o[(size_t)row * rs + cbo + 16] = cl.u;
                }
            }
        }
    } else if constexpr (OMODE == 1) {
        float* C = (float*)Cout;
        float lacc = 0.f;
#pragma unroll
        for (int fm = 0; fm < FM; ++fm) {
#pragma unroll
            for (int nt = 0; nt < 2; ++nt) {
                const int col = n0 + wn * 64 + nt * 32 + l31;
                const float b = bias[col];
#pragma unroll
                for (int rg = 0; rg < 16; ++rg) {
                    const int row = row0 + wm * MR + fm * 32 + (rg & 3) + 8 * (rg >> 2) + 4 * lh;
                    float v = acc[fm][nt][rg] + b;
                    if (RELU) v = v > 0.f ? v : 0.f;
                    C[(size_t)row * N + col] = v;
                    float d = v - X[(size_t)row * N + col];
                    lacc = fmaf(d, d, lacc);
                }
            }
        }
        __shared__ float red[512];
        red[tid] = lacc;
        __syncthreads();
        for (int s = 256; s > 0; s >>= 1) {
            if (tid < s) red[tid] += red[tid + s];
            __syncthreads();
        }
        if (tid == 0) lossP[by * gridDim.x + bx] = red[0];
    } else if constexpr (OMODE == 2) {
        float* C = (float*)Cout;
#pragma unroll
        for (int fm = 0; fm < FM; ++fm) {
#pragma unroll
            for (int nt = 0; nt < 2; ++nt) {
                const int col = n0 + wn * 64 + nt * 32 + l31;
#pragma unroll
                for (int rg = 0; rg < 16; ++rg) {
                    const int row = row0 + wm * MR + fm * 32 + (rg & 3) + 8 * (rg >> 2) + 4 * lh;
                    C[(size_t)row * ldc + col] = acc[fm][nt][rg];
                }
            }
        }
    } else {
        // OMODE 3: Gram — write G6[pair][prow][qcol]
        float* C = (float*)Cout + (size_t)pair * 65536;
#pragma unroll
        for (int fm = 0; fm < FM; ++fm) {
#pragma unroll
            for (int nt = 0; nt < 2; ++nt) {
                const int colL = wn * 64 + nt * 32 + l31;
#pragma unroll
                for (int rg = 0; rg < 16; ++rg) {
                    const int row = wm * MR + fm * 32 + (rg & 3) + 8 * (rg >> 2) + 4 * lh;
                    C[(size_t)row * 256 + colL] = acc[fm][nt][rg];
                }
            }
        }
    }
}

// ---------------------------------------------------------------------------
// Sequential Gram-corrected argmax over scores S [rows][1024] (R10-proven).
// ---------------------------------------------------------------------------
__global__ __launch_bounds__(256)
void vq_argmax(const float* __restrict__ S,
               const float* __restrict__ G6,
               const float* __restrict__ cnorm,
               float* __restrict__ idx_out,
               int* __restrict__ idxi,
               float* __restrict__ sstar,
               int rowbase)
{
    const int tid = threadIdx.x, wid = tid >> 6, lane = tid & 63;
    const int lrow = blockIdx.x * 4 + wid;
    const int grow = rowbase + lrow;
    const float* srow = S + (size_t)lrow * 1024;
    const int c0 = lane * 4;

    int iprev0 = 0, iprev1 = 0, iprev2 = 0;

#pragma unroll
    for (int q = 0; q < NQ; ++q) {
        float4 sv = *reinterpret_cast<const float4*>(srow + q * 256 + c0);
        float a[4] = {sv.x, sv.y, sv.z, sv.w};
        if (q >= 1) {
            const float* g = G6 + ((size_t)(q - 1) * 256 + iprev0) * 256 + c0;
            float4 gv = *reinterpret_cast<const float4*>(g);
            a[0] -= gv.x; a[1] -= gv.y; a[2] -= gv.z; a[3] -= gv.w;
        }
        if (q >= 2) {
            const float* g = G6 + ((size_t)(q + 1) * 256 + iprev1) * 256 + c0;
            float4 gv = *reinterpret_cast<const float4*>(g);
            a[0] -= gv.x; a[1] -= gv.y; a[2] -= gv.z; a[3] -= gv.w;
        }
        if (q >= 3) {
            const float* g = G6 + ((size_t)5 * 256 + iprev2) * 256 + c0;
            float4 gv = *reinterpret_cast<const float4*>(g);
            a[0] -= gv.x; a[1] -= gv.y; a[2] -= gv.z; a[3] -= gv.w;
        }
        float4 cnv = *reinterpret_cast<const float4*>(cnorm + q * 256 + c0);
        float cna[4] = {cnv.x, cnv.y, cnv.z, cnv.w};

        float bv = -FLT_MAX;
        int   bi = 0;
#pragma unroll
        for (int j = 0; j < 4; ++j) {
            float s = 2.f * a[j] - cna[j];
            const int code = c0 + j;
            if (s > bv || (s == bv && code < bi)) { bv = s; bi = code; }
        }
#pragma unroll
        for (int m = 1; m < 64; m <<= 1) {
            float ov = __shfl_xor(bv, m, 64);
            int   oi = __shfl_xor(bi, m, 64);
            if (ov > bv || (ov == bv && oi < bi)) { bv = ov; bi = oi; }
        }
        if (q == 0) iprev0 = bi;
        else if (q == 1) iprev1 = bi;
        else if (q == 2) iprev2 = bi;
        if (lane == 0) {
            idxi[q * 65536 + grow]  = bi;
            sstar[q * 65536 + grow] = bv;
            idx_out[(size_t)grow * NQ + q] = (float)bi;
        }
    }
}

// ---------------------------------------------------------------------------
__global__ __launch_bounds__(256)
void vq_quant(const int* __restrict__ idxi, const float* __restrict__ sstar,
              const float* __restrict__ zn, const float* __restrict__ cb,
              unsigned short* __restrict__ qout, float* __restrict__ commitP)
{
    __shared__ float red[256];
    const int tid = threadIdx.x, wid = tid >> 6, lane = tid & 63;
    float ca = 0.f;

#pragma unroll
    for (int t = 0; t < 8; ++t) {
        const int row = blockIdx.x * 32 + wid * 8 + t;
        const int i0 = idxi[row],          i1 = idxi[65536 + row];
        const int i2 = idxi[131072 + row], i3 = idxi[196608 + row];
        const int koff = lane * 8;
        const float* c0 = cb + ((size_t)(0 * NCODE + i0)) * HDIM + koff;
        const float* c1 = cb + ((size_t)(1 * NCODE + i1)) * HDIM + koff;
        const float* c2 = cb + ((size_t)(2 * NCODE + i2)) * HDIM + koff;
        const float* c3 = cb + ((size_t)(3 * NCODE + i3)) * HDIM + koff;
        float q[8];
#pragma unroll
        for (int hh = 0; hh < 2; ++hh) {
            float4 v0 = *reinterpret_cast<const float4*>(c0 + hh * 4);
            float4 v1 = *reinterpret_cast<const float4*>(c1 + hh * 4);
            float4 v2 = *reinterpret_cast<const float4*>(c2 + hh * 4);
            float4 v3 = *reinterpret_cast<const float4*>(c3 + hh * 4);
            q[hh * 4 + 0] = ((v0.x + v1.x) + v2.x) + v3.x;
            q[hh * 4 + 1] = ((v0.y + v1.y) + v2.y) + v3.y;
            q[hh * 4 + 2] = ((v0.z + v1.z) + v2.z) + v3.z;
            q[hh * 4 + 3] = ((v0.w + v1.w) + v2.w) + v3.w;
        }
        half8 oh, ol;
        cvt_hl8(q, oh, ol);
        unsigned short* op = qout + (size_t)row * 1024
                                  + (lane >> 1) * 32 + (lane & 1) * 8;
        *reinterpret_cast<half8*>(op)      = oh;
        *reinterpret_cast<half8*>(op + 16) = ol;

        if (lane == 0) {
            float rn = zn[row];
            rn -= sstar[row];           float cm = rn;
            rn -= sstar[65536 + row];   cm += rn;
            rn -= sstar[131072 + row];  cm += rn;
            rn -= sstar[196608 + row];  cm += rn;
            ca += cm;
        }
    }

    red[tid] = ca;
    __syncthreads();
    for (int s = 128; s > 0; s >>= 1) {
        if (tid < s) red[tid] += red[tid + s];
        __syncthreads();
    }
    if (tid == 0) commitP[blockIdx.x] = red[0];
}

// ---------------------------------------------------------------------------
__global__ __launch_bounds__(256)
void loss_reduce(const float* __restrict__ cP, int nc,
                 const float* __restrict__ rP, int nr,
                 float* __restrict__ out2)
{
    __shared__ float red[256];
    const int tid = threadIdx.x;

    float s = 0.f;
    for (int i = tid; i < nc; i += 256) s += cP[i];
    red[tid] = s;
    __syncthreads();
    for (int st = 128; st > 0; st >>= 1) {
        if (tid < st) red[tid] += red[tid + st];
        __syncthreads();
    }
    float ctot = red[0];
    __syncthreads();

    s = 0.f;
    for (int i = tid; i < nr; i += 256) s += rP[i];
    red[tid] = s;
    __syncthreads();
    for (int st = 128; st > 0; st >>= 1) {
        if (tid < st) red[tid] += red[tid + st];
        __syncthreads();
    }
    if (tid == 0) {
        out2[0] = red[0] / ((float)BATCH * (float)EDIM);
        out2[1] = 0.25f * ctot / ((float)BATCH * (float)HDIM);
    }
}

// ---------------------------------------------------------------------------
extern "C" void kernel_launch(void* const* d_in, const int* in_sizes, int n_in,
                              void* d_out, int out_size, void* d_ws, size_t ws_size,
                              hipStream_t stream)
{
    const float* x   = (const float*)d_in[0];
    const float* ew1 = (const float*)d_in[1];
    const float* eb1 = (const float*)d_in[2];
    const float* ew2 = (const float*)d_in[3];
    const float* eb2 = (const float*)d_in[4];
    const float* cb  = (const float*)d_in[5];
    const float* dw1 = (const float*)d_in[6];
    const float* db1 = (const float*)d_in[7];
    const float* dw2 = (const float*)d_in[8];
    const float* db2 = (const float*)d_in[9];

    float* out = (float*)d_out;
    float* ws  = (float*)d_ws;
    unsigned short* P0  = (unsigned short*)(ws + WS_P0);
    unsigned short* P1  = (unsigned short*)(ws + WS_P1);
    unsigned short* XS  = P1;
    float* Sbuf = ws + WS_P0;
    unsigned short* cbw = (unsigned short*)(ws + WS_CBW);
    unsigned short* cba = (unsigned short*)(ws + WS_CBA);
    float* G6 = ws + WS_G6;
    float* zn = ws + WS_ZN;
    float* ss = ws + WS_SSTAR;
    int*   ii = (int*)(ws + WS_IDXI);
    float* cn = ws + WS_CNORM;
    float* cP = ws + WS_COMMITP;
    float* rP = ws + WS_RECONP;
    unsigned short* w1s = (unsigned short*)(ws + WS_W1S);
    unsigned short* w2s = (unsigned short*)(ws + WS_W2S);
    unsigned short* w3s = (unsigned short*)(ws + WS_W3S);
    unsigned short* w4s = (unsigned short*)(ws + WS_W4S);

    // prep
    cnorm_kernel<<<NQ * NCODE, 64, 0, stream>>>(cb, cn);
    split_act<<<BATCH * 48 / 256, 256, 0, stream>>>(x, XS, EDIM);
    split_wall<<<960, 256, 0, stream>>>(ew1, ew2, dw1, dw2, cb,
                                        w1s, w2s, w3s, w4s, cbw, cba);

    // Gram: one dispatch, 6 blocks
    gemm_pl<256, 32, 3, false><<<dim3(6, 1), 512, 0, stream>>>(
        cba, cbw, nullptr, G6, nullptr, nullptr, 1024, 256);

    // encoder: x-split (P1) -> h1-split (P0) -> z-split (P1)
    gemm_pl<256, 24, 0, true><<<dim3(HDIM / 256, BATCH / 256), 512, 0, stream>>>(
        XS, w1s, eb1, P0, nullptr, nullptr, HDIM, HDIM);
    gemm_pl<256, 32, 0, false><<<dim3(HDIM / 256, BATCH / 256), 512, 0, stream>>>(
        P0, w2s, eb2, P1, nullptr, nullptr, HDIM, HDIM);

    // |z|^2 per row
    rownorm<<<BATCH / 4, 256, 0, stream>>>(P1, zn);

    // fused score GEMM (N=1024) + streaming argmax, two half-batch passes
    float* idxo = out + OUT_IDX_OFF;
    for (int half = 0; half < 2; ++half) {
        const int rowbase = half * 32768;
        gemm_pl<256, 32, 2, false><<<dim3(4, 128), 512, 0, stream>>>(
            P1 + (size_t)rowbase * 1024, cbw, nullptr, Sbuf,
            nullptr, nullptr, 1024, 1024);
        vq_argmax<<<8192, 256, 0, stream>>>(Sbuf, G6, cn, idxo, ii, ss, rowbase);
    }

    // quant = sum of chosen codes -> P0 (split), + commit partials
    vq_quant<<<BATCH / 32, 256, 0, stream>>>(ii, ss, zn, cb, P0, cP);

    // decoder: quant (P0) -> hidden (P1) -> recon (out) + loss
    gemm_pl<256, 32, 0, true><<<dim3(HDIM / 256, BATCH / 256), 512, 0, stream>>>(
        P0, w3s, db1, P1, nullptr, nullptr, HDIM, HDIM);
    gemm_pl<128, 32, 1, false><<<dim3(EDIM / 128, BATCH / 256), 512, 0, stream>>>(
        P1, w4s, db2, out, x, rP, EDIM, EDIM);

    // losses
    loss_reduce<<<1, 256, 0, stream>>>(cP, BATCH / 32, rP,
                                       (EDIM / 128) * (BATCH / 256),
                                       out + OUT_RL_OFF);
}